// Round 7
// baseline (282.974 us; speedup 1.0000x reference)
//
#include <hip/hip_runtime.h>
#include <hip/hip_bf16.h>

typedef _Float16 f16x8 __attribute__((ext_vector_type(8)));
typedef _Float16 h2    __attribute__((ext_vector_type(2)));
typedef float    f32x4v __attribute__((ext_vector_type(4)));
typedef float    f32x2 __attribute__((ext_vector_type(2)));

#define NEG_SLOPE 0.2f

__device__ __forceinline__ ushort f2h_bits(float f){ _Float16 h=(_Float16)f; return __builtin_bit_cast(ushort, h); }
__device__ __forceinline__ h2 uash2(unsigned u){ return __builtin_bit_cast(h2, u); }
__device__ __forceinline__ h2 habs(h2 v){ return __builtin_bit_cast(h2, __builtin_bit_cast(unsigned, v) & 0x7fff7fffu); }
__device__ __forceinline__ float lrelu(float v){ return fmaxf(v,0.f) + NEG_SLOPE*fminf(v,0.f); }

// ---------------- K0: prep — Wt (f16), Web (f16), att6/att4 (f16), deg/attr_sum/etype ----------------
__global__ __launch_bounds__(256) void k_prep(const float* __restrict__ Wl, const float* __restrict__ Wr,
    const float* __restrict__ We, const float* __restrict__ att,
    ushort* __restrict__ Wt, ushort* __restrict__ Web, ushort* __restrict__ att6, ushort* __restrict__ att4,
    const int* __restrict__ dst, const float* __restrict__ ea,
    int* __restrict__ deg_i, float* __restrict__ attr_sum, unsigned char* __restrict__ etype_e, int E)
{
    int idx = blockIdx.x*256 + threadIdx.x;
    if (idx < 256*128) {
        int c = idx >> 7, k = idx & 127;
        float v = (c < 128) ? Wl[k*128 + c] : Wr[k*128 + (c-128)];
        Wt[idx] = f2h_bits(v);
    }
    if (idx < 8*128) Web[idx] = f2h_bits(We[idx]);
    if (idx < 128)  { att6[idx] = f2h_bits(0.6f*att[idx]); att4[idx] = f2h_bits(0.4f*att[idx]); }
    if (idx >= E) return;
    int d = dst[idx];
    atomicAdd(&deg_i[d], 1);
    const float* a = ea + (size_t)idx*8;
    float4 u0 = *(const float4*)a;
    float4 u1 = *(const float4*)(a + 4);
    float v[8] = {u0.x,u0.y,u0.z,u0.w,u1.x,u1.y,u1.z,u1.w};
    float best = 0.f; int bt = 0;                 // one-hot: find the nonzero component
    #pragma unroll
    for (int j=0;j<8;++j)
        if (fabsf(v[j]) > fabsf(best)) { best = v[j]; bt = j; }
    etype_e[idx] = (unsigned char)bt;
    if (best != 0.f) atomicAdd(&attr_sum[(size_t)d*8 + bt], best);
}

// ---------------- K1: single-kernel scan (block scan + atomic base) ----------------
__global__ __launch_bounds__(256) void k_scan(const int* __restrict__ deg_i, int* __restrict__ csr_off,
                                              int* __restrict__ gtotal)
{
    __shared__ int s[256];
    __shared__ int sbase;
    int i = blockIdx.x*256 + threadIdx.x;
    int v = deg_i[i];
    s[threadIdx.x] = v;
    __syncthreads();
    #pragma unroll
    for (int off=1; off<256; off<<=1){
        int t = (threadIdx.x >= off) ? s[threadIdx.x-off] : 0;
        __syncthreads();
        s[threadIdx.x] += t;
        __syncthreads();
    }
    if (threadIdx.x == 255) sbase = atomicAdd(gtotal, s[255]);
    __syncthreads();
    csr_off[i] = s[threadIdx.x] - v + sbase;      // exclusive global offset (segment order arbitrary)
}

// ---------------- K2: MFMA GEMM  xl|xr = x @ [Wl|Wr] + [bl|br]  (f16) ----------------
__global__ __launch_bounds__(256) void k_gemm(const float* __restrict__ x, const ushort* __restrict__ Wt,
    const float* __restrict__ bl, const float* __restrict__ br,
    ushort* __restrict__ xl, ushort* __restrict__ xr, int Nn)
{
    __shared__ ushort As[64*128];                 // 16KB f16 bits, XOR-swizzled 16B granules
    int tid = threadIdx.x;
    int wave = tid >> 6, lane = tid & 63;
    int l15 = lane & 15, l4 = lane >> 4;
    int row0 = blockIdx.x * 64;

    #pragma unroll
    for (int it = 0; it < 4; ++it) {
        int idx = tid + it*256;                   // granule id (8 cols each), 1024 total
        int r = idx >> 4;
        int g = idx & 15;
        float4 a = make_float4(0,0,0,0), b = make_float4(0,0,0,0);
        int g_row = row0 + r;
        if (g_row < Nn) {
            const float* p = x + (size_t)g_row*128 + g*8;
            a = *(const float4*)p;
            b = *(const float4*)(p + 4);
        }
        union { ushort us[8]; uint4 v; } P;
        P.us[0]=f2h_bits(a.x); P.us[1]=f2h_bits(a.y); P.us[2]=f2h_bits(a.z); P.us[3]=f2h_bits(a.w);
        P.us[4]=f2h_bits(b.x); P.us[5]=f2h_bits(b.y); P.us[6]=f2h_bits(b.z); P.us[7]=f2h_bits(b.w);
        int sw = (g*16) ^ ((r & 7) << 4);
        *(uint4*)((char*)As + r*256 + sw) = P.v;
    }
    __syncthreads();

    f16x8 bfrag[4][4];
    #pragma unroll
    for (int nf = 0; nf < 4; ++nf) {
        int col = wave*64 + nf*16 + l15;
        const ushort* bp = Wt + (size_t)col*128;
        #pragma unroll
        for (int ks = 0; ks < 4; ++ks)
            bfrag[ks][nf] = *(const f16x8*)(const void*)(bp + ks*32 + l4*8);
    }
    f32x4v acc[4][4];
    #pragma unroll
    for (int i=0;i<4;++i)
        #pragma unroll
        for (int j=0;j<4;++j) acc[i][j] = (f32x4v){0.f,0.f,0.f,0.f};

    #pragma unroll
    for (int ks = 0; ks < 4; ++ks) {
        f16x8 afrag[4];
        #pragma unroll
        for (int mf = 0; mf < 4; ++mf) {
            int r = mf*16 + l15;
            int kbyte = ks*64 + l4*16;
            afrag[mf] = *(const f16x8*)(const void*)((char*)As + r*256 + (kbyte ^ ((r&7)<<4)));
        }
        #pragma unroll
        for (int mf = 0; mf < 4; ++mf)
            #pragma unroll
            for (int nf = 0; nf < 4; ++nf)
                acc[mf][nf] = __builtin_amdgcn_mfma_f32_16x16x32_f16(afrag[mf], bfrag[ks][nf], acc[mf][nf], 0,0,0);
    }
    #pragma unroll
    for (int mf = 0; mf < 4; ++mf) {
        #pragma unroll
        for (int nf = 0; nf < 4; ++nf) {
            int col = wave*64 + nf*16 + l15;
            float bias = (col < 128) ? bl[col] : br[col-128];
            #pragma unroll
            for (int r = 0; r < 4; ++r) {
                int row = row0 + mf*16 + l4*4 + r;
                if (row < Nn) {
                    ushort o = f2h_bits(acc[mf][nf][r] + bias);
                    if (col < 128) xl[(size_t)row*128 + col] = o;
                    else           xr[(size_t)row*128 + (col-128)] = o;
                }
            }
        }
    }
}

// ---------------- K3: CSR fill, packed src|etype ----------------
__global__ __launch_bounds__(256) void k_fill(const int* __restrict__ src, const int* __restrict__ dst,
    const unsigned char* __restrict__ etype_e,
    int* __restrict__ cursor, const int* __restrict__ csr_off, int* __restrict__ csr_pack, int E)
{
    int e = blockIdx.x*256 + threadIdx.x;
    if (e >= E) return;
    int d = dst[e];
    int slot = csr_off[d] + atomicAdd(&cursor[d], 1);
    csr_pack[slot] = src[e] | ((int)etype_e[e] << 24);
}

// ---------------- K4: fused per-node pass, packed f16, 4 edges in flight, grid-stride waves ----------------
// lane: g = lane>>4 (edge slot), l = lane&15 (channels l*8..l*8+7, head l>>1)
__global__ __launch_bounds__(256) void k_node(const int* __restrict__ deg_i, const int* __restrict__ csr_off,
    const int* __restrict__ csr_pack,
    const ushort* __restrict__ xl, const ushort* __restrict__ xr, const ushort* __restrict__ Web,
    const ushort* __restrict__ att6, const ushort* __restrict__ att4,
    const float* __restrict__ att, const float* __restrict__ attr_sum,
    const float* __restrict__ bias, const float* __restrict__ lnw, const float* __restrict__ lnb,
    float* __restrict__ out, int Nn)
{
    int lane = threadIdx.x & 63;
    int g = lane >> 4, l = lane & 15;
    int gw = (blockIdx.x*256 + threadIdx.x) >> 6;
    int nwaves = gridDim.x * 4;

    h2 a6[4], a4[4];
    {
        uint4 u6 = *(const uint4*)(att6 + l*8);
        uint4 u4 = *(const uint4*)(att4 + l*8);
        a6[0]=uash2(u6.x); a6[1]=uash2(u6.y); a6[2]=uash2(u6.z); a6[3]=uash2(u6.w);
        a4[0]=uash2(u4.x); a4[1]=uash2(u4.y); a4[2]=uash2(u4.z); a4[3]=uash2(u4.w);
    }

    for (int n = gw; n < Nn; n += nwaves) {
        h2 xr2[4];
        {
            uint4 ru = *(const uint4*)(xr + (size_t)n*128 + l*8);
            xr2[0]=uash2(ru.x); xr2[1]=uash2(ru.y); xr2[2]=uash2(ru.z); xr2[3]=uash2(ru.w);
        }
        int beg = csr_off[n];
        int cnt = deg_i[n];
        f32x2 acc2[4];
        #pragma unroll
        for (int k=0;k<4;++k) acc2[k] = (f32x2){0.f,0.f};
        float den = 0.f;

        #pragma unroll 2
        for (int i = 0; i < cnt; i += 4) {
            bool valid = (i + g) < cnt;
            int packed = csr_pack[beg + (valid ? i + g : 0)];
            int sidx = packed & 0xFFFFFF;
            int et = ((unsigned)packed) >> 24;
            uint4 xu = *(const uint4*)(xl + (size_t)sidx*128 + l*8);
            uint4 wu = *(const uint4*)(Web + (size_t)et*128 + l*8);
            h2 xs[4] = {uash2(xu.x), uash2(xu.y), uash2(xu.z), uash2(xu.w)};
            h2 ws[4] = {uash2(wu.x), uash2(wu.y), uash2(wu.z), uash2(wu.w)};
            float p = 0.f;
            f32x2 xf[4];
            #pragma unroll
            for (int k=0;k<4;++k){
                h2 v = (xs[k] + xr2[k]) + ws[k];
                p = __builtin_amdgcn_fdot2(a6[k], v, p, false);
                p = __builtin_amdgcn_fdot2(a4[k], habs(v), p, false);
                xf[k] = __builtin_convertvector(xs[k], f32x2);
            }
            p += __shfl_xor(p, 1);                              // head score (2 lanes/head)
            float ex = valid ? __expf(p) : 0.f;
            den += ex;
            #pragma unroll
            for (int k=0;k<4;++k) acc2[k] += ex * xf[k];
        }

        // cross-edge-group reduce
        #pragma unroll
        for (int k=0;k<4;++k){
            acc2[k].x += __shfl_xor(acc2[k].x, 16); acc2[k].x += __shfl_xor(acc2[k].x, 32);
            acc2[k].y += __shfl_xor(acc2[k].y, 16); acc2[k].y += __shfl_xor(acc2[k].y, 32);
        }
        den += __shfl_xor(den, 16);
        den += __shfl_xor(den, 32);

        // self loop (f32 path, once per node)
        {
            f32x2 xsf[4], xrf[4], av[4], emb[4];
            uint4 su = *(const uint4*)(xl + (size_t)n*128 + l*8);
            xsf[0]=__builtin_convertvector(uash2(su.x), f32x2); xsf[1]=__builtin_convertvector(uash2(su.y), f32x2);
            xsf[2]=__builtin_convertvector(uash2(su.z), f32x2); xsf[3]=__builtin_convertvector(uash2(su.w), f32x2);
            #pragma unroll
            for (int k=0;k<4;++k){ xrf[k]=__builtin_convertvector(xr2[k], f32x2); emb[k]=(f32x2){0.f,0.f}; }
            float4 a0 = *(const float4*)(att + l*8);
            float4 a1 = *(const float4*)(att + l*8 + 4);
            av[0]=(f32x2){a0.x,a0.y}; av[1]=(f32x2){a0.z,a0.w}; av[2]=(f32x2){a1.x,a1.y}; av[3]=(f32x2){a1.z,a1.w};
            float inv = 1.f / fmaxf((float)cnt, 1.f);
            #pragma unroll
            for (int t=0;t<8;++t){
                float w = attr_sum[(size_t)n*8 + t] * inv;
                uint4 wu = *(const uint4*)(Web + t*128 + l*8);
                emb[0] += w*__builtin_convertvector(uash2(wu.x), f32x2);
                emb[1] += w*__builtin_convertvector(uash2(wu.y), f32x2);
                emb[2] += w*__builtin_convertvector(uash2(wu.z), f32x2);
                emb[3] += w*__builtin_convertvector(uash2(wu.w), f32x2);
            }
            float p = 0.f;
            #pragma unroll
            for (int k=0;k<4;++k){
                f32x2 v = xsf[k] + xrf[k] + emb[k];
                p += av[k].x*lrelu(v.x) + av[k].y*lrelu(v.y);
            }
            p += __shfl_xor(p, 1);
            float ex = __expf(p);
            den += ex;
            #pragma unroll
            for (int k=0;k<4;++k) acc2[k] += ex * xsf[k];
        }

        float dinv = 1.f/den;
        f32x2 a[4];
        {
            float4 b0 = *(const float4*)(bias + l*8);
            float4 b1 = *(const float4*)(bias + l*8 + 4);
            a[0] = acc2[0]*dinv + (f32x2){b0.x,b0.y};
            a[1] = acc2[1]*dinv + (f32x2){b0.z,b0.w};
            a[2] = acc2[2]*dinv + (f32x2){b1.x,b1.y};
            a[3] = acc2[3]*dinv + (f32x2){b1.z,b1.w};
        }
        float sum = 0.f;
        #pragma unroll
        for (int k=0;k<4;++k) sum += a[k].x + a[k].y;
        #pragma unroll
        for (int off=8; off>0; off>>=1) sum += __shfl_xor(sum, off);
        float mu = sum * (1.f/128.f);
        float vs = 0.f;
        #pragma unroll
        for (int k=0;k<4;++k){ a[k] -= mu; vs += a[k].x*a[k].x + a[k].y*a[k].y; }
        #pragma unroll
        for (int off=8; off>0; off>>=1) vs += __shfl_xor(vs, off);
        float rs = rsqrtf(vs*(1.f/128.f) + 1e-5f);
        float y[8];
        {
            float4 w0 = *(const float4*)(lnw + l*8);
            float4 w1 = *(const float4*)(lnw + l*8 + 4);
            float4 c0 = *(const float4*)(lnb + l*8);
            float4 c1 = *(const float4*)(lnb + l*8 + 4);
            y[0]=a[0].x*rs*w0.x+c0.x; y[1]=a[0].y*rs*w0.y+c0.y;
            y[2]=a[1].x*rs*w0.z+c0.z; y[3]=a[1].y*rs*w0.w+c0.w;
            y[4]=a[2].x*rs*w1.x+c1.x; y[5]=a[2].y*rs*w1.y+c1.y;
            y[6]=a[3].x*rs*w1.z+c1.z; y[7]=a[3].y*rs*w1.w+c1.w;
        }
        #pragma unroll
        for (int j=0;j<8;++j) y[j] = (y[j] > 0.f) ? y[j] : (__expf(y[j]) - 1.f);
        if (lane < 16) {
            float* po = out + (size_t)n*128 + l*8;
            *(float4*)po     = make_float4(y[0],y[1],y[2],y[3]);
            *(float4*)(po+4) = make_float4(y[4],y[5],y[6],y[7]);
        }
    }
}

extern "C" void kernel_launch(void* const* d_in, const int* in_sizes, int n_in,
                              void* d_out, int out_size, void* d_ws, size_t ws_size,
                              hipStream_t stream)
{
    const float* x   = (const float*)d_in[0];
    const int*   src = (const int*)  d_in[1];
    const int*   dst = (const int*)  d_in[2];
    const float* ea  = (const float*)d_in[3];
    const float* Wl  = (const float*)d_in[4];
    const float* bl  = (const float*)d_in[5];
    const float* Wr  = (const float*)d_in[6];
    const float* br  = (const float*)d_in[7];
    const float* We  = (const float*)d_in[8];
    const float* att = (const float*)d_in[9];
    const float* bias= (const float*)d_in[10];
    const float* lnw = (const float*)d_in[11];
    const float* lnb = (const float*)d_in[12];
    float* out = (float*)d_out;

    const int N  = in_sizes[0] / 128;
    const int E  = in_sizes[1];
    const int NP = ((N + 255)/256)*256;
    const int MB = (N + 63)/64;
    const int SB = NP/256;
    const int EB = (E + 255)/256;

    char* base = (char*)d_ws;
    size_t o = 0;
    auto alloc = [&](size_t b){ size_t r = o; o += (b + 255) & ~(size_t)255; return r; };
    ushort* Wt       = (ushort*)(base + alloc(256*128*2));
    ushort* Web      = (ushort*)(base + alloc(8*128*2));
    ushort* att6     = (ushort*)(base + alloc(128*2));
    ushort* att4     = (ushort*)(base + alloc(128*2));
    ushort* xl       = (ushort*)(base + alloc((size_t)MB*64*128*2));
    ushort* xr       = (ushort*)(base + alloc((size_t)MB*64*128*2));
    size_t zoff = o;
    int*    deg_i    = (int*)   (base + alloc((size_t)NP*4));
    int*    cursor   = (int*)   (base + alloc((size_t)NP*4));
    float*  attr_sum = (float*) (base + alloc((size_t)NP*8*4));
    int*    gtotal   = (int*)   (base + alloc(256));
    size_t zbytes = o - zoff;
    int*    csr_off  = (int*)   (base + alloc((size_t)NP*4));
    int*    csr_pack = (int*)   (base + alloc((size_t)E*4));
    unsigned char* etype_e = (unsigned char*)(base + alloc((size_t)E));
    (void)ws_size; (void)n_in; (void)out_size;

    hipMemsetAsync(base + zoff, 0, zbytes, stream);
    k_prep <<<EB, 256, 0, stream>>>(Wl, Wr, We, att, Wt, Web, att6, att4, dst, ea, deg_i, attr_sum, etype_e, E);
    k_scan <<<SB, 256, 0, stream>>>(deg_i, csr_off, gtotal);
    k_gemm <<<MB, 256, 0, stream>>>(x, Wt, bl, br, xl, xr, N);
    k_fill <<<EB, 256, 0, stream>>>(src, dst, etype_e, cursor, csr_off, csr_pack, E);
    k_node <<<1024, 256, 0, stream>>>(deg_i, csr_off, csr_pack, xl, xr, Web, att6, att4, att, attr_sum,
                                      bias, lnw, lnb, out, N);
}

// Round 8
// 239.578 us; speedup vs baseline: 1.1811x; 1.1811x over previous
//
#include <hip/hip_runtime.h>
#include <hip/hip_bf16.h>

typedef _Float16 f16x8 __attribute__((ext_vector_type(8)));
typedef _Float16 h2    __attribute__((ext_vector_type(2)));
typedef float    f32x4v __attribute__((ext_vector_type(4)));
typedef float    f32x2 __attribute__((ext_vector_type(2)));

#define NEG_SLOPE 0.2f

__device__ __forceinline__ ushort f2h_bits(float f){ _Float16 h=(_Float16)f; return __builtin_bit_cast(ushort, h); }
__device__ __forceinline__ h2 uash2(unsigned u){ return __builtin_bit_cast(h2, u); }
__device__ __forceinline__ float lrelu(float v){ return fmaxf(v,0.f) + NEG_SLOPE*fminf(v,0.f); }

// ---------------- K0: prep — Wt (f16), Web (f16), att_h (f16), deg/attr_sum/etype ----------------
__global__ __launch_bounds__(256) void k_prep(const float* __restrict__ Wl, const float* __restrict__ Wr,
    const float* __restrict__ We, const float* __restrict__ att,
    ushort* __restrict__ Wt, ushort* __restrict__ Web, ushort* __restrict__ att_h,
    const int* __restrict__ dst, const float* __restrict__ ea,
    int* __restrict__ deg_i, float* __restrict__ attr_sum, unsigned char* __restrict__ etype_e, int E)
{
    int idx = blockIdx.x*256 + threadIdx.x;
    if (idx < 256*128) {
        int c = idx >> 7, k = idx & 127;
        float v = (c < 128) ? Wl[k*128 + c] : Wr[k*128 + (c-128)];
        Wt[idx] = f2h_bits(v);
    }
    if (idx < 8*128) Web[idx] = f2h_bits(We[idx]);
    if (idx < 128)   att_h[idx] = f2h_bits(att[idx]);
    if (idx >= E) return;
    int d = dst[idx];
    atomicAdd(&deg_i[d], 1);
    const float* a = ea + (size_t)idx*8;
    float4 u0 = *(const float4*)a;
    float4 u1 = *(const float4*)(a + 4);
    float v[8] = {u0.x,u0.y,u0.z,u0.w,u1.x,u1.y,u1.z,u1.w};
    float best = 0.f; int bt = 0;                 // one-hot: find the nonzero component
    #pragma unroll
    for (int j=0;j<8;++j)
        if (fabsf(v[j]) > fabsf(best)) { best = v[j]; bt = j; }
    etype_e[idx] = (unsigned char)bt;
    if (best != 0.f) atomicAdd(&attr_sum[(size_t)d*8 + bt], best);
}

// ---------------- K1: single-kernel scan (block scan + atomic base); emits csr_off + csr_next ----------------
__global__ __launch_bounds__(256) void k_scan(const int* __restrict__ deg_i, int* __restrict__ csr_off,
                                              int* __restrict__ csr_next, int* __restrict__ gtotal)
{
    __shared__ int s[256];
    __shared__ int sbase;
    int i = blockIdx.x*256 + threadIdx.x;
    int v = deg_i[i];
    s[threadIdx.x] = v;
    __syncthreads();
    #pragma unroll
    for (int off=1; off<256; off<<=1){
        int t = (threadIdx.x >= off) ? s[threadIdx.x-off] : 0;
        __syncthreads();
        s[threadIdx.x] += t;
        __syncthreads();
    }
    if (threadIdx.x == 255) sbase = atomicAdd(gtotal, s[255]);
    __syncthreads();
    int o = s[threadIdx.x] - v + sbase;           // exclusive global offset (segment order arbitrary)
    csr_off[i]  = o;
    csr_next[i] = o;
}

// ---------------- K2: MFMA GEMM (swapped operands -> row-major 8B packed stores) ----------------
__global__ __launch_bounds__(256) void k_gemm(const float* __restrict__ x, const ushort* __restrict__ Wt,
    const float* __restrict__ bl, const float* __restrict__ br,
    ushort* __restrict__ xl, ushort* __restrict__ xr, int Nn)
{
    __shared__ ushort As[64*128];                 // 16KB f16 bits, XOR-swizzled 16B granules
    int tid = threadIdx.x;
    int wave = tid >> 6, lane = tid & 63;
    int l15 = lane & 15, l4 = lane >> 4;
    int row0 = blockIdx.x * 64;

    #pragma unroll
    for (int it = 0; it < 4; ++it) {
        int idx = tid + it*256;                   // granule id (8 cols each), 1024 total
        int r = idx >> 4;
        int g = idx & 15;
        float4 a = make_float4(0,0,0,0), b = make_float4(0,0,0,0);
        int g_row = row0 + r;
        if (g_row < Nn) {
            const float* p = x + (size_t)g_row*128 + g*8;
            a = *(const float4*)p;
            b = *(const float4*)(p + 4);
        }
        union { ushort us[8]; uint4 v; } P;
        P.us[0]=f2h_bits(a.x); P.us[1]=f2h_bits(a.y); P.us[2]=f2h_bits(a.z); P.us[3]=f2h_bits(a.w);
        P.us[4]=f2h_bits(b.x); P.us[5]=f2h_bits(b.y); P.us[6]=f2h_bits(b.z); P.us[7]=f2h_bits(b.w);
        int sw = (g*16) ^ ((r & 7) << 4);
        *(uint4*)((char*)As + r*256 + sw) = P.v;
    }
    __syncthreads();

    f16x8 bfrag[4][4];
    #pragma unroll
    for (int nf = 0; nf < 4; ++nf) {
        int col = wave*64 + nf*16 + l15;
        const ushort* bp = Wt + (size_t)col*128;
        #pragma unroll
        for (int ks = 0; ks < 4; ++ks)
            bfrag[ks][nf] = *(const f16x8*)(const void*)(bp + ks*32 + l4*8);
    }
    f32x4v acc[4][4];
    #pragma unroll
    for (int i=0;i<4;++i)
        #pragma unroll
        for (int j=0;j<4;++j) acc[i][j] = (f32x4v){0.f,0.f,0.f,0.f};

    #pragma unroll
    for (int ks = 0; ks < 4; ++ks) {
        f16x8 afrag[4];
        #pragma unroll
        for (int mf = 0; mf < 4; ++mf) {
            int r = mf*16 + l15;
            int kbyte = ks*64 + l4*16;
            afrag[mf] = *(const f16x8*)(const void*)((char*)As + r*256 + (kbyte ^ ((r&7)<<4)));
        }
        // swapped operands: result tile is D^T in the C-layout ->
        // lane holds D[row = mf*16 + l15][cols = wave*64 + nf*16 + l4*4 + 0..3]
        #pragma unroll
        for (int mf = 0; mf < 4; ++mf)
            #pragma unroll
            for (int nf = 0; nf < 4; ++nf)
                acc[mf][nf] = __builtin_amdgcn_mfma_f32_16x16x32_f16(bfrag[ks][nf], afrag[mf], acc[mf][nf], 0,0,0);
    }
    #pragma unroll
    for (int mf = 0; mf < 4; ++mf) {
        int row = row0 + mf*16 + l15;
        if (row >= Nn) continue;
        #pragma unroll
        for (int nf = 0; nf < 4; ++nf) {
            int col0 = wave*64 + nf*16 + l4*4;    // 4 consecutive cols, all in same half
            bool left = (col0 < 128);
            float4 bv = left ? *(const float4*)(bl + col0) : *(const float4*)(br + (col0-128));
            h2 p0 = { (_Float16)(acc[mf][nf][0] + bv.x), (_Float16)(acc[mf][nf][1] + bv.y) };
            h2 p1 = { (_Float16)(acc[mf][nf][2] + bv.z), (_Float16)(acc[mf][nf][3] + bv.w) };
            uint2 st = make_uint2(__builtin_bit_cast(unsigned, p0), __builtin_bit_cast(unsigned, p1));
            ushort* dstp = (left ? xl : xr) + (size_t)row*128 + (col0 & 127);
            *(uint2*)dstp = st;
        }
    }
}

// ---------------- K3: CSR fill, packed src|etype (atomics directly on csr_next) ----------------
__global__ __launch_bounds__(256) void k_fill(const int* __restrict__ src, const int* __restrict__ dst,
    const unsigned char* __restrict__ etype_e,
    int* __restrict__ csr_next, int* __restrict__ csr_pack, int E)
{
    int e = blockIdx.x*256 + threadIdx.x;
    if (e >= E) return;
    int d = dst[e];
    int slot = atomicAdd(&csr_next[d], 1);
    csr_pack[slot] = src[e] | ((int)etype_e[e] << 24);
}

// ---------------- K4: fused per-node pass, packed f16, 4 edges in flight (R6 structure, 2 waves/block) ----------------
// lane: g = lane>>4 (edge slot), l = lane&15 (channels l*8..l*8+7, head l>>1)
__global__ __launch_bounds__(128) void k_node(const int* __restrict__ deg_i, const int* __restrict__ csr_off,
    const int* __restrict__ csr_pack,
    const ushort* __restrict__ xl, const ushort* __restrict__ xr, const ushort* __restrict__ Web,
    const ushort* __restrict__ att_h, const float* __restrict__ att, const float* __restrict__ attr_sum,
    const float* __restrict__ bias, const float* __restrict__ lnw, const float* __restrict__ lnb,
    float* __restrict__ out, int Nn)
{
    int wv = threadIdx.x >> 6, lane = threadIdx.x & 63;
    int n = blockIdx.x*2 + wv;
    if (n >= Nn) return;
    int g = lane >> 4, l = lane & 15;

    h2 xr2[4], at2[4];
    {
        uint4 ru = *(const uint4*)(xr + (size_t)n*128 + l*8);
        uint4 au = *(const uint4*)(att_h + l*8);
        xr2[0]=uash2(ru.x); xr2[1]=uash2(ru.y); xr2[2]=uash2(ru.z); xr2[3]=uash2(ru.w);
        at2[0]=uash2(au.x); at2[1]=uash2(au.y); at2[2]=uash2(au.z); at2[3]=uash2(au.w);
    }
    const h2 z2  = {(_Float16)0.f, (_Float16)0.f};
    const h2 c02 = {(_Float16)NEG_SLOPE, (_Float16)NEG_SLOPE};

    int beg = csr_off[n];
    int cnt = deg_i[n];
    f32x2 acc2[4];
    #pragma unroll
    for (int k=0;k<4;++k) acc2[k] = (f32x2){0.f,0.f};
    float den = 0.f;

    #pragma unroll 2
    for (int i = 0; i < cnt; i += 4) {
        bool valid = (i + g) < cnt;
        int packed = csr_pack[beg + (valid ? i + g : 0)];
        int sidx = packed & 0xFFFFFF;
        int et = ((unsigned)packed) >> 24;
        uint4 xu = *(const uint4*)(xl + (size_t)sidx*128 + l*8);
        uint4 wu = *(const uint4*)(Web + (size_t)et*128 + l*8);
        h2 xs[4] = {uash2(xu.x), uash2(xu.y), uash2(xu.z), uash2(xu.w)};
        h2 ws[4] = {uash2(wu.x), uash2(wu.y), uash2(wu.z), uash2(wu.w)};
        float p = 0.f;
        f32x2 xf[4];
        #pragma unroll
        for (int k=0;k<4;++k){
            h2 v = (xs[k] + xr2[k]) + ws[k];
            h2 r = __builtin_elementwise_max(v, z2);
            h2 m = __builtin_elementwise_min(v, z2);
            r = r + c02*m;                                  // pk_fma
            p = __builtin_amdgcn_fdot2(at2[k], r, p, false);
            xf[k] = __builtin_convertvector(xs[k], f32x2);
        }
        p += __shfl_xor(p, 1);                              // head score (2 lanes/head)
        float ex = valid ? __expf(p) : 0.f;
        den += ex;
        #pragma unroll
        for (int k=0;k<4;++k) acc2[k] += ex * xf[k];
    }

    // cross-edge-group reduce: all 4 groups identical after this
    #pragma unroll
    for (int k=0;k<4;++k){
        acc2[k].x += __shfl_xor(acc2[k].x, 16); acc2[k].x += __shfl_xor(acc2[k].x, 32);
        acc2[k].y += __shfl_xor(acc2[k].y, 16); acc2[k].y += __shfl_xor(acc2[k].y, 32);
    }
    den += __shfl_xor(den, 16);
    den += __shfl_xor(den, 32);

    // self loop (f32 path, once per node)
    {
        f32x2 xsf[4], xrf[4], av[4], emb[4];
        uint4 su = *(const uint4*)(xl + (size_t)n*128 + l*8);
        xsf[0]=__builtin_convertvector(uash2(su.x), f32x2); xsf[1]=__builtin_convertvector(uash2(su.y), f32x2);
        xsf[2]=__builtin_convertvector(uash2(su.z), f32x2); xsf[3]=__builtin_convertvector(uash2(su.w), f32x2);
        #pragma unroll
        for (int k=0;k<4;++k){ xrf[k]=__builtin_convertvector(xr2[k], f32x2); emb[k]=(f32x2){0.f,0.f}; }
        float4 a0 = *(const float4*)(att + l*8);
        float4 a1 = *(const float4*)(att + l*8 + 4);
        av[0]=(f32x2){a0.x,a0.y}; av[1]=(f32x2){a0.z,a0.w}; av[2]=(f32x2){a1.x,a1.y}; av[3]=(f32x2){a1.z,a1.w};
        float inv = 1.f / fmaxf((float)cnt, 1.f);
        #pragma unroll
        for (int t=0;t<8;++t){
            float w = attr_sum[(size_t)n*8 + t] * inv;
            uint4 wu = *(const uint4*)(Web + t*128 + l*8);
            emb[0] += w*__builtin_convertvector(uash2(wu.x), f32x2);
            emb[1] += w*__builtin_convertvector(uash2(wu.y), f32x2);
            emb[2] += w*__builtin_convertvector(uash2(wu.z), f32x2);
            emb[3] += w*__builtin_convertvector(uash2(wu.w), f32x2);
        }
        float p = 0.f;
        #pragma unroll
        for (int k=0;k<4;++k){
            f32x2 v = xsf[k] + xrf[k] + emb[k];
            p += av[k].x*lrelu(v.x) + av[k].y*lrelu(v.y);
        }
        p += __shfl_xor(p, 1);
        float ex = __expf(p);
        den += ex;
        #pragma unroll
        for (int k=0;k<4;++k) acc2[k] += ex * xsf[k];
    }

    float dinv = 1.f/den;
    f32x2 a[4];
    {
        float4 b0 = *(const float4*)(bias + l*8);
        float4 b1 = *(const float4*)(bias + l*8 + 4);
        a[0] = acc2[0]*dinv + (f32x2){b0.x,b0.y};
        a[1] = acc2[1]*dinv + (f32x2){b0.z,b0.w};
        a[2] = acc2[2]*dinv + (f32x2){b1.x,b1.y};
        a[3] = acc2[3]*dinv + (f32x2){b1.z,b1.w};
    }
    float sum = 0.f;
    #pragma unroll
    for (int k=0;k<4;++k) sum += a[k].x + a[k].y;
    #pragma unroll
    for (int off=8; off>0; off>>=1) sum += __shfl_xor(sum, off);
    float mu = sum * (1.f/128.f);
    float vs = 0.f;
    #pragma unroll
    for (int k=0;k<4;++k){ a[k] -= mu; vs += a[k].x*a[k].x + a[k].y*a[k].y; }
    #pragma unroll
    for (int off=8; off>0; off>>=1) vs += __shfl_xor(vs, off);
    float rs = rsqrtf(vs*(1.f/128.f) + 1e-5f);
    float y[8];
    {
        float4 w0 = *(const float4*)(lnw + l*8);
        float4 w1 = *(const float4*)(lnw + l*8 + 4);
        float4 c0 = *(const float4*)(lnb + l*8);
        float4 c1 = *(const float4*)(lnb + l*8 + 4);
        y[0]=a[0].x*rs*w0.x+c0.x; y[1]=a[0].y*rs*w0.y+c0.y;
        y[2]=a[1].x*rs*w0.z+c0.z; y[3]=a[1].y*rs*w0.w+c0.w;
        y[4]=a[2].x*rs*w1.x+c1.x; y[5]=a[2].y*rs*w1.y+c1.y;
        y[6]=a[3].x*rs*w1.z+c1.z; y[7]=a[3].y*rs*w1.w+c1.w;
    }
    #pragma unroll
    for (int j=0;j<8;++j) y[j] = (y[j] > 0.f) ? y[j] : (__expf(y[j]) - 1.f);
    if (lane < 16) {
        float* po = out + (size_t)n*128 + l*8;
        *(float4*)po     = make_float4(y[0],y[1],y[2],y[3]);
        *(float4*)(po+4) = make_float4(y[4],y[5],y[6],y[7]);
    }
}

extern "C" void kernel_launch(void* const* d_in, const int* in_sizes, int n_in,
                              void* d_out, int out_size, void* d_ws, size_t ws_size,
                              hipStream_t stream)
{
    const float* x   = (const float*)d_in[0];
    const int*   src = (const int*)  d_in[1];
    const int*   dst = (const int*)  d_in[2];
    const float* ea  = (const float*)d_in[3];
    const float* Wl  = (const float*)d_in[4];
    const float* bl  = (const float*)d_in[5];
    const float* Wr  = (const float*)d_in[6];
    const float* br  = (const float*)d_in[7];
    const float* We  = (const float*)d_in[8];
    const float* att = (const float*)d_in[9];
    const float* bias= (const float*)d_in[10];
    const float* lnw = (const float*)d_in[11];
    const float* lnb = (const float*)d_in[12];
    float* out = (float*)d_out;

    const int N  = in_sizes[0] / 128;
    const int E  = in_sizes[1];
    const int NP = ((N + 255)/256)*256;
    const int MB = (N + 63)/64;
    const int SB = NP/256;
    const int EB = (E + 255)/256;

    char* base = (char*)d_ws;
    size_t o = 0;
    auto alloc = [&](size_t b){ size_t r = o; o += (b + 255) & ~(size_t)255; return r; };
    ushort* Wt       = (ushort*)(base + alloc(256*128*2));
    ushort* Web      = (ushort*)(base + alloc(8*128*2));
    ushort* att_h    = (ushort*)(base + alloc(128*2));
    ushort* xl       = (ushort*)(base + alloc((size_t)MB*64*128*2));
    ushort* xr       = (ushort*)(base + alloc((size_t)MB*64*128*2));
    size_t zoff = o;
    int*    deg_i    = (int*)   (base + alloc((size_t)NP*4));
    float*  attr_sum = (float*) (base + alloc((size_t)NP*8*4));
    int*    gtotal   = (int*)   (base + alloc(256));
    size_t zbytes = o - zoff;
    int*    csr_off  = (int*)   (base + alloc((size_t)NP*4));
    int*    csr_next = (int*)   (base + alloc((size_t)NP*4));
    int*    csr_pack = (int*)   (base + alloc((size_t)E*4));
    unsigned char* etype_e = (unsigned char*)(base + alloc((size_t)E));
    (void)ws_size; (void)n_in; (void)out_size;

    hipMemsetAsync(base + zoff, 0, zbytes, stream);
    k_prep <<<EB, 256, 0, stream>>>(Wl, Wr, We, att, Wt, Web, att_h, dst, ea, deg_i, attr_sum, etype_e, E);
    k_scan <<<SB, 256, 0, stream>>>(deg_i, csr_off, csr_next, gtotal);
    k_gemm <<<MB, 256, 0, stream>>>(x, Wt, bl, br, xl, xr, N);
    k_fill <<<EB, 256, 0, stream>>>(src, dst, etype_e, csr_next, csr_pack, E);
    k_node <<<(N+1)/2, 128, 0, stream>>>(deg_i, csr_off, csr_pack, xl, xr, Web, att_h, att, attr_sum,
                                         bias, lnw, lnb, out, N);
}

// Round 9
// 236.524 us; speedup vs baseline: 1.1964x; 1.0129x over previous
//
#include <hip/hip_runtime.h>
#include <hip/hip_bf16.h>

typedef _Float16 f16x8 __attribute__((ext_vector_type(8)));
typedef _Float16 h2    __attribute__((ext_vector_type(2)));
typedef float    f32x4v __attribute__((ext_vector_type(4)));
typedef float    f32x2 __attribute__((ext_vector_type(2)));

#define NEG_SLOPE 0.2f

__device__ __forceinline__ ushort f2h_bits(float f){ _Float16 h=(_Float16)f; return __builtin_bit_cast(ushort, h); }
__device__ __forceinline__ h2 uash2(unsigned u){ return __builtin_bit_cast(h2, u); }
__device__ __forceinline__ float lrelu(float v){ return fmaxf(v,0.f) + NEG_SLOPE*fminf(v,0.f); }

// ---------------- K0: prep — Wt (f16), Web (f16), att_h (f16), deg/attr_sum/etype ----------------
__global__ __launch_bounds__(256) void k_prep(const float* __restrict__ Wl, const float* __restrict__ Wr,
    const float* __restrict__ We, const float* __restrict__ att,
    ushort* __restrict__ Wt, ushort* __restrict__ Web, ushort* __restrict__ att_h,
    const int* __restrict__ dst, const float* __restrict__ ea,
    int* __restrict__ deg_i, float* __restrict__ attr_sum, unsigned char* __restrict__ etype_e, int E)
{
    int idx = blockIdx.x*256 + threadIdx.x;
    if (idx < 256*128) {
        int c = idx >> 7, k = idx & 127;
        float v = (c < 128) ? Wl[k*128 + c] : Wr[k*128 + (c-128)];
        Wt[idx] = f2h_bits(v);
    }
    if (idx < 8*128) Web[idx] = f2h_bits(We[idx]);
    if (idx < 128)   att_h[idx] = f2h_bits(att[idx]);
    if (idx >= E) return;
    int d = dst[idx];
    atomicAdd(&deg_i[d], 1);
    const float* a = ea + (size_t)idx*8;
    float4 u0 = *(const float4*)a;
    float4 u1 = *(const float4*)(a + 4);
    float v[8] = {u0.x,u0.y,u0.z,u0.w,u1.x,u1.y,u1.z,u1.w};
    float best = 0.f; int bt = 0;                 // one-hot: find the nonzero component
    #pragma unroll
    for (int j=0;j<8;++j)
        if (fabsf(v[j]) > fabsf(best)) { best = v[j]; bt = j; }
    etype_e[idx] = (unsigned char)bt;
    if (best != 0.f) atomicAdd(&attr_sum[(size_t)d*8 + bt], best);
}

// ---------------- K1: single-kernel scan (block scan + atomic base); emits csr_off + csr_next ----------------
__global__ __launch_bounds__(256) void k_scan(const int* __restrict__ deg_i, int* __restrict__ csr_off,
                                              int* __restrict__ csr_next, int* __restrict__ gtotal)
{
    __shared__ int s[256];
    __shared__ int sbase;
    int i = blockIdx.x*256 + threadIdx.x;
    int v = deg_i[i];
    s[threadIdx.x] = v;
    __syncthreads();
    #pragma unroll
    for (int off=1; off<256; off<<=1){
        int t = (threadIdx.x >= off) ? s[threadIdx.x-off] : 0;
        __syncthreads();
        s[threadIdx.x] += t;
        __syncthreads();
    }
    if (threadIdx.x == 255) sbase = atomicAdd(gtotal, s[255]);
    __syncthreads();
    int o = s[threadIdx.x] - v + sbase;           // exclusive global offset (segment order arbitrary)
    csr_off[i]  = o;
    csr_next[i] = o;
}

// ---------------- K2: MFMA GEMM, LDS-staged coalesced epilogue ----------------
__global__ __launch_bounds__(256) void k_gemm(const float* __restrict__ x, const ushort* __restrict__ Wt,
    const float* __restrict__ bl, const float* __restrict__ br,
    ushort* __restrict__ xl, ushort* __restrict__ xr, int Nn)
{
    __shared__ ushort As[64*128];                 // 16KB: input staging, then output staging
    int tid = threadIdx.x;
    int wave = tid >> 6, lane = tid & 63;
    int l15 = lane & 15, l4 = lane >> 4;
    int row0 = blockIdx.x * 64;

    #pragma unroll
    for (int it = 0; it < 4; ++it) {
        int idx = tid + it*256;                   // granule id (8 cols each), 1024 total
        int r = idx >> 4;
        int g = idx & 15;
        float4 a = make_float4(0,0,0,0), b = make_float4(0,0,0,0);
        int g_row = row0 + r;
        if (g_row < Nn) {
            const float* p = x + (size_t)g_row*128 + g*8;
            a = *(const float4*)p;
            b = *(const float4*)(p + 4);
        }
        union { ushort us[8]; uint4 v; } P;
        P.us[0]=f2h_bits(a.x); P.us[1]=f2h_bits(a.y); P.us[2]=f2h_bits(a.z); P.us[3]=f2h_bits(a.w);
        P.us[4]=f2h_bits(b.x); P.us[5]=f2h_bits(b.y); P.us[6]=f2h_bits(b.z); P.us[7]=f2h_bits(b.w);
        int sw = (g*16) ^ ((r & 7) << 4);
        *(uint4*)((char*)As + r*256 + sw) = P.v;
    }
    __syncthreads();

    f16x8 bfrag[4][4];
    #pragma unroll
    for (int nf = 0; nf < 4; ++nf) {
        int col = wave*64 + nf*16 + l15;
        const ushort* bp = Wt + (size_t)col*128;
        #pragma unroll
        for (int ks = 0; ks < 4; ++ks)
            bfrag[ks][nf] = *(const f16x8*)(const void*)(bp + ks*32 + l4*8);
    }
    f32x4v acc[4][4];
    #pragma unroll
    for (int i=0;i<4;++i)
        #pragma unroll
        for (int j=0;j<4;++j) acc[i][j] = (f32x4v){0.f,0.f,0.f,0.f};

    #pragma unroll
    for (int ks = 0; ks < 4; ++ks) {
        f16x8 afrag[4];
        #pragma unroll
        for (int mf = 0; mf < 4; ++mf) {
            int r = mf*16 + l15;
            int kbyte = ks*64 + l4*16;
            afrag[mf] = *(const f16x8*)(const void*)((char*)As + r*256 + (kbyte ^ ((r&7)<<4)));
        }
        // swapped operands: lane holds D[row = mf*16 + l15][cols = wave*64 + nf*16 + l4*4 + 0..3]
        #pragma unroll
        for (int mf = 0; mf < 4; ++mf)
            #pragma unroll
            for (int nf = 0; nf < 4; ++nf)
                acc[mf][nf] = __builtin_amdgcn_mfma_f32_16x16x32_f16(bfrag[ks][nf], afrag[mf], acc[mf][nf], 0,0,0);
    }

    // Epilogue: per half (xl cols 0..127 from waves 0,1 | xr cols from waves 2,3):
    // stage f16 results in LDS (8B-granule XOR swizzle), then stream full rows coalesced.
    #pragma unroll
    for (int h = 0; h < 2; ++h) {
        __syncthreads();
        if ((wave >> 1) == h) {
            const float* bp = h ? br : bl;
            #pragma unroll
            for (int mf = 0; mf < 4; ++mf) {
                int row = mf*16 + l15;
                #pragma unroll
                for (int nf = 0; nf < 4; ++nf) {
                    int colL = (wave & 1)*64 + nf*16 + l4*4;   // in-half col, mult of 4
                    float4 bv = *(const float4*)(bp + colL);
                    h2 p0 = { (_Float16)(acc[mf][nf][0] + bv.x), (_Float16)(acc[mf][nf][1] + bv.y) };
                    h2 p1 = { (_Float16)(acc[mf][nf][2] + bv.z), (_Float16)(acc[mf][nf][3] + bv.w) };
                    int sw = colL ^ ((row & 7) << 2);          // 8B-granule swizzle (ushort units)
                    uint2 st = make_uint2(__builtin_bit_cast(unsigned, p0), __builtin_bit_cast(unsigned, p1));
                    *(uint2*)(&As[row*128 + sw]) = st;
                }
            }
        }
        __syncthreads();
        ushort* dbuf = h ? xr : xl;
        #pragma unroll
        for (int it = 0; it < 4; ++it) {
            int chunk = tid + it*256;             // 1024 chunks = 64 rows x 16 x 8 ushorts
            int row = chunk >> 4;
            int c0 = (chunk & 15) * 8;
            int grow = row0 + row;
            if (grow < Nn) {
                int s0 = c0 ^ ((row & 7) << 2);
                int s1 = (c0 + 4) ^ ((row & 7) << 2);
                uint2 a = *(const uint2*)(&As[row*128 + s0]);
                uint2 b = *(const uint2*)(&As[row*128 + s1]);
                *(uint4*)(dbuf + (size_t)grow*128 + c0) = make_uint4(a.x, a.y, b.x, b.y);
            }
        }
    }
}

// ---------------- K3: CSR fill, packed src|etype (atomics directly on csr_next) ----------------
__global__ __launch_bounds__(256) void k_fill(const int* __restrict__ src, const int* __restrict__ dst,
    const unsigned char* __restrict__ etype_e,
    int* __restrict__ csr_next, int* __restrict__ csr_pack, int E)
{
    int e = blockIdx.x*256 + threadIdx.x;
    if (e >= E) return;
    int d = dst[e];
    int slot = atomicAdd(&csr_next[d], 1);
    csr_pack[slot] = src[e] | ((int)etype_e[e] << 24);
}

// ---------------- K4: fused per-node pass, packed f16, 4 edges in flight, 2 waves/block ----------------
// lane: g = lane>>4 (edge slot), l = lane&15 (channels l*8..l*8+7, head l>>1)
__global__ __launch_bounds__(128) void k_node(const int* __restrict__ deg_i, const int* __restrict__ csr_off,
    const int* __restrict__ csr_pack,
    const ushort* __restrict__ xl, const ushort* __restrict__ xr, const ushort* __restrict__ Web,
    const ushort* __restrict__ att_h, const float* __restrict__ att, const float* __restrict__ attr_sum,
    const float* __restrict__ bias, const float* __restrict__ lnw, const float* __restrict__ lnb,
    float* __restrict__ out, int Nn)
{
    int wv = threadIdx.x >> 6, lane = threadIdx.x & 63;
    int n = blockIdx.x*2 + wv;
    if (n >= Nn) return;
    int g = lane >> 4, l = lane & 15;

    h2 xr2[4], at2[4];
    {
        uint4 ru = *(const uint4*)(xr + (size_t)n*128 + l*8);
        uint4 au = *(const uint4*)(att_h + l*8);
        xr2[0]=uash2(ru.x); xr2[1]=uash2(ru.y); xr2[2]=uash2(ru.z); xr2[3]=uash2(ru.w);
        at2[0]=uash2(au.x); at2[1]=uash2(au.y); at2[2]=uash2(au.z); at2[3]=uash2(au.w);
    }
    const h2 z2  = {(_Float16)0.f, (_Float16)0.f};
    const h2 c02 = {(_Float16)NEG_SLOPE, (_Float16)NEG_SLOPE};

    int beg = csr_off[n];
    int cnt = deg_i[n];
    f32x2 acc2[4];
    #pragma unroll
    for (int k=0;k<4;++k) acc2[k] = (f32x2){0.f,0.f};
    float den = 0.f;

    #pragma unroll 2
    for (int i = 0; i < cnt; i += 4) {
        bool valid = (i + g) < cnt;
        int packed = csr_pack[beg + (valid ? i + g : 0)];
        int sidx = packed & 0xFFFFFF;
        int et = ((unsigned)packed) >> 24;
        uint4 xu = *(const uint4*)(xl + (size_t)sidx*128 + l*8);
        uint4 wu = *(const uint4*)(Web + (size_t)et*128 + l*8);
        h2 xs[4] = {uash2(xu.x), uash2(xu.y), uash2(xu.z), uash2(xu.w)};
        h2 ws[4] = {uash2(wu.x), uash2(wu.y), uash2(wu.z), uash2(wu.w)};
        float p = 0.f;
        f32x2 xf[4];
        #pragma unroll
        for (int k=0;k<4;++k){
            h2 v = (xs[k] + xr2[k]) + ws[k];
            h2 r = __builtin_elementwise_max(v, z2);
            h2 m = __builtin_elementwise_min(v, z2);
            r = r + c02*m;                                  // pk_fma
            p = __builtin_amdgcn_fdot2(at2[k], r, p, false);
            xf[k] = __builtin_convertvector(xs[k], f32x2);
        }
        p += __shfl_xor(p, 1);                              // head score (2 lanes/head)
        float ex = valid ? __expf(p) : 0.f;
        den += ex;
        #pragma unroll
        for (int k=0;k<4;++k) acc2[k] += ex * xf[k];
    }

    // cross-edge-group reduce: all 4 groups identical after this
    #pragma unroll
    for (int k=0;k<4;++k){
        acc2[k].x += __shfl_xor(acc2[k].x, 16); acc2[k].x += __shfl_xor(acc2[k].x, 32);
        acc2[k].y += __shfl_xor(acc2[k].y, 16); acc2[k].y += __shfl_xor(acc2[k].y, 32);
    }
    den += __shfl_xor(den, 16);
    den += __shfl_xor(den, 32);

    // self loop (f32 path, once per node)
    {
        f32x2 xsf[4], xrf[4], av[4], emb[4];
        uint4 su = *(const uint4*)(xl + (size_t)n*128 + l*8);
        xsf[0]=__builtin_convertvector(uash2(su.x), f32x2); xsf[1]=__builtin_convertvector(uash2(su.y), f32x2);
        xsf[2]=__builtin_convertvector(uash2(su.z), f32x2); xsf[3]=__builtin_convertvector(uash2(su.w), f32x2);
        #pragma unroll
        for (int k=0;k<4;++k){ xrf[k]=__builtin_convertvector(xr2[k], f32x2); emb[k]=(f32x2){0.f,0.f}; }
        float4 a0 = *(const float4*)(att + l*8);
        float4 a1 = *(const float4*)(att + l*8 + 4);
        av[0]=(f32x2){a0.x,a0.y}; av[1]=(f32x2){a0.z,a0.w}; av[2]=(f32x2){a1.x,a1.y}; av[3]=(f32x2){a1.z,a1.w};
        float inv = 1.f / fmaxf((float)cnt, 1.f);
        #pragma unroll
        for (int t=0;t<8;++t){
            float w = attr_sum[(size_t)n*8 + t] * inv;
            uint4 wu = *(const uint4*)(Web + t*128 + l*8);
            emb[0] += w*__builtin_convertvector(uash2(wu.x), f32x2);
            emb[1] += w*__builtin_convertvector(uash2(wu.y), f32x2);
            emb[2] += w*__builtin_convertvector(uash2(wu.z), f32x2);
            emb[3] += w*__builtin_convertvector(uash2(wu.w), f32x2);
        }
        float p = 0.f;
        #pragma unroll
        for (int k=0;k<4;++k){
            f32x2 v = xsf[k] + xrf[k] + emb[k];
            p += av[k].x*lrelu(v.x) + av[k].y*lrelu(v.y);
        }
        p += __shfl_xor(p, 1);
        float ex = __expf(p);
        den += ex;
        #pragma unroll
        for (int k=0;k<4;++k) acc2[k] += ex * xsf[k];
    }

    float dinv = 1.f/den;
    f32x2 a[4];
    {
        float4 b0 = *(const float4*)(bias + l*8);
        float4 b1 = *(const float4*)(bias + l*8 + 4);
        a[0] = acc2[0]*dinv + (f32x2){b0.x,b0.y};
        a[1] = acc2[1]*dinv + (f32x2){b0.z,b0.w};
        a[2] = acc2[2]*dinv + (f32x2){b1.x,b1.y};
        a[3] = acc2[3]*dinv + (f32x2){b1.z,b1.w};
    }
    float sum = 0.f;
    #pragma unroll
    for (int k=0;k<4;++k) sum += a[k].x + a[k].y;
    #pragma unroll
    for (int off=8; off>0; off>>=1) sum += __shfl_xor(sum, off);
    float mu = sum * (1.f/128.f);
    float vs = 0.f;
    #pragma unroll
    for (int k=0;k<4;++k){ a[k] -= mu; vs += a[k].x*a[k].x + a[k].y*a[k].y; }
    #pragma unroll
    for (int off=8; off>0; off>>=1) vs += __shfl_xor(vs, off);
    float rs = rsqrtf(vs*(1.f/128.f) + 1e-5f);
    float y[8];
    {
        float4 w0 = *(const float4*)(lnw + l*8);
        float4 w1 = *(const float4*)(lnw + l*8 + 4);
        float4 c0 = *(const float4*)(lnb + l*8);
        float4 c1 = *(const float4*)(lnb + l*8 + 4);
        y[0]=a[0].x*rs*w0.x+c0.x; y[1]=a[0].y*rs*w0.y+c0.y;
        y[2]=a[1].x*rs*w0.z+c0.z; y[3]=a[1].y*rs*w0.w+c0.w;
        y[4]=a[2].x*rs*w1.x+c1.x; y[5]=a[2].y*rs*w1.y+c1.y;
        y[6]=a[3].x*rs*w1.z+c1.z; y[7]=a[3].y*rs*w1.w+c1.w;
    }
    #pragma unroll
    for (int j=0;j<8;++j) y[j] = (y[j] > 0.f) ? y[j] : (__expf(y[j]) - 1.f);
    if (lane < 16) {
        float* po = out + (size_t)n*128 + l*8;
        *(float4*)po     = make_float4(y[0],y[1],y[2],y[3]);
        *(float4*)(po+4) = make_float4(y[4],y[5],y[6],y[7]);
    }
}

extern "C" void kernel_launch(void* const* d_in, const int* in_sizes, int n_in,
                              void* d_out, int out_size, void* d_ws, size_t ws_size,
                              hipStream_t stream)
{
    const float* x   = (const float*)d_in[0];
    const int*   src = (const int*)  d_in[1];
    const int*   dst = (const int*)  d_in[2];
    const float* ea  = (const float*)d_in[3];
    const float* Wl  = (const float*)d_in[4];
    const float* bl  = (const float*)d_in[5];
    const float* Wr  = (const float*)d_in[6];
    const float* br  = (const float*)d_in[7];
    const float* We  = (const float*)d_in[8];
    const float* att = (const float*)d_in[9];
    const float* bias= (const float*)d_in[10];
    const float* lnw = (const float*)d_in[11];
    const float* lnb = (const float*)d_in[12];
    float* out = (float*)d_out;

    const int N  = in_sizes[0] / 128;
    const int E  = in_sizes[1];
    const int NP = ((N + 255)/256)*256;
    const int MB = (N + 63)/64;
    const int SB = NP/256;
    const int EB = (E + 255)/256;

    char* base = (char*)d_ws;
    size_t o = 0;
    auto alloc = [&](size_t b){ size_t r = o; o += (b + 255) & ~(size_t)255; return r; };
    ushort* Wt       = (ushort*)(base + alloc(256*128*2));
    ushort* Web      = (ushort*)(base + alloc(8*128*2));
    ushort* att_h    = (ushort*)(base + alloc(128*2));
    ushort* xl       = (ushort*)(base + alloc((size_t)MB*64*128*2));
    ushort* xr       = (ushort*)(base + alloc((size_t)MB*64*128*2));
    size_t zoff = o;
    int*    deg_i    = (int*)   (base + alloc((size_t)NP*4));
    float*  attr_sum = (float*) (base + alloc((size_t)NP*8*4));
    int*    gtotal   = (int*)   (base + alloc(256));
    size_t zbytes = o - zoff;
    int*    csr_off  = (int*)   (base + alloc((size_t)NP*4));
    int*    csr_next = (int*)   (base + alloc((size_t)NP*4));
    int*    csr_pack = (int*)   (base + alloc((size_t)E*4));
    unsigned char* etype_e = (unsigned char*)(base + alloc((size_t)E));
    (void)ws_size; (void)n_in; (void)out_size;

    hipMemsetAsync(base + zoff, 0, zbytes, stream);
    k_prep <<<EB, 256, 0, stream>>>(Wl, Wr, We, att, Wt, Web, att_h, dst, ea, deg_i, attr_sum, etype_e, E);
    k_scan <<<SB, 256, 0, stream>>>(deg_i, csr_off, csr_next, gtotal);
    k_gemm <<<MB, 256, 0, stream>>>(x, Wt, bl, br, xl, xr, N);
    k_fill <<<EB, 256, 0, stream>>>(src, dst, etype_e, csr_next, csr_pack, E);
    k_node <<<(N+1)/2, 128, 0, stream>>>(deg_i, csr_off, csr_pack, xl, xr, Web, att_h, att, attr_sum,
                                         bias, lnw, lnb, out, N);
}

// Round 10
// 221.745 us; speedup vs baseline: 1.2761x; 1.0666x over previous
//
#include <hip/hip_runtime.h>
#include <hip/hip_bf16.h>

typedef _Float16 f16x8 __attribute__((ext_vector_type(8)));
typedef _Float16 h2    __attribute__((ext_vector_type(2)));
typedef float    f32x4v __attribute__((ext_vector_type(4)));
typedef float    f32x2 __attribute__((ext_vector_type(2)));

#define NEG_SLOPE 0.2f

__device__ __forceinline__ ushort f2h_bits(float f){ _Float16 h=(_Float16)f; return __builtin_bit_cast(ushort, h); }
__device__ __forceinline__ h2 uash2(unsigned u){ return __builtin_bit_cast(h2, u); }
__device__ __forceinline__ float lrelu(float v){ return fmaxf(v,0.f) + NEG_SLOPE*fminf(v,0.f); }

// ---------------- K0: prep — Wt (f16), Web (f16), att_h (f16), cnt64/etype (ONE atomic per edge) ----------------
__global__ __launch_bounds__(256) void k_prep(const float* __restrict__ Wl, const float* __restrict__ Wr,
    const float* __restrict__ We, const float* __restrict__ att,
    ushort* __restrict__ Wt, ushort* __restrict__ Web, ushort* __restrict__ att_h,
    const int* __restrict__ dst, const float* __restrict__ ea,
    unsigned long long* __restrict__ cnt64, unsigned char* __restrict__ etype_e, int E)
{
    int idx = blockIdx.x*256 + threadIdx.x;
    if (idx < 256*128) {
        int c = idx >> 7, k = idx & 127;
        float v = (c < 128) ? Wl[k*128 + c] : Wr[k*128 + (c-128)];
        Wt[idx] = f2h_bits(v);
    }
    if (idx < 8*128) Web[idx] = f2h_bits(We[idx]);
    if (idx < 128)   att_h[idx] = f2h_bits(att[idx]);
    if (idx >= E) return;
    int d = dst[idx];
    const float* a = ea + (size_t)idx*8;
    float4 u0 = *(const float4*)a;
    float4 u1 = *(const float4*)(a + 4);
    float v[8] = {u0.x,u0.y,u0.z,u0.w,u1.x,u1.y,u1.z,u1.w};
    int bt = 0;                                   // one-hot: find the nonzero component (value==1.0)
    #pragma unroll
    for (int j=0;j<8;++j) if (v[j] != 0.f) bt = j;
    etype_e[idx] = (unsigned char)bt;
    atomicAdd(&cnt64[d], 1ull << (8*bt));         // per-type count; deg = byte-sum
}

// ---------------- K1: scan — deg from cnt64, block scan + atomic base; emits deg/csr_off/csr_next ----------------
__global__ __launch_bounds__(256) void k_scan(const unsigned long long* __restrict__ cnt64,
                                              int* __restrict__ deg_i, int* __restrict__ csr_off,
                                              int* __restrict__ csr_next, int* __restrict__ gtotal)
{
    __shared__ int s[256];
    __shared__ int sbase;
    int i = blockIdx.x*256 + threadIdx.x;
    unsigned long long cv = cnt64[i];
    int v = (int)((cv * 0x0101010101010101ull) >> 56);   // byte sum = degree
    deg_i[i] = v;
    s[threadIdx.x] = v;
    __syncthreads();
    #pragma unroll
    for (int off=1; off<256; off<<=1){
        int t = (threadIdx.x >= off) ? s[threadIdx.x-off] : 0;
        __syncthreads();
        s[threadIdx.x] += t;
        __syncthreads();
    }
    if (threadIdx.x == 255) sbase = atomicAdd(gtotal, s[255]);
    __syncthreads();
    int o = s[threadIdx.x] - v + sbase;           // exclusive global offset (segment order arbitrary)
    csr_off[i]  = o;
    csr_next[i] = o;
}

// ---------------- K2: barrier-light MFMA GEMM — wave-independent 16-row strips ----------------
// Wave w: rows row0 = (blk*4+w)*16. A global->reg (each x elem once), B streamed from L2-hot Wt.
// D staged in wave-private LDS slice (swizzled), then coalesced 256B-row stores.
__global__ __launch_bounds__(256) void k_gemm(const float* __restrict__ x, const ushort* __restrict__ Wt,
    const float* __restrict__ bl, const float* __restrict__ br,
    ushort* __restrict__ xl, ushort* __restrict__ xr, int Nn)
{
    __shared__ ushort S[4][16*256];               // 8KB per wave
    int tid = threadIdx.x;
    int wave = tid >> 6, lane = tid & 63;
    int l15 = lane & 15, l4 = lane >> 4;
    int row0 = blockIdx.x*64 + wave*16;

    // A fragments: lane holds x[row0+l15][k = ks*32 + l4*8 .. +7] as f16
    f16x8 afrag[4];
    int grow = row0 + l15;
    bool rok = grow < Nn;
    const float* xp = x + (size_t)grow*128 + l4*8;
    #pragma unroll
    for (int ks=0; ks<4; ++ks){
        float4 a = make_float4(0,0,0,0), b = make_float4(0,0,0,0);
        if (rok) { a = *(const float4*)(xp + ks*32); b = *(const float4*)(xp + ks*32 + 4); }
        afrag[ks] = (f16x8){ (_Float16)a.x,(_Float16)a.y,(_Float16)a.z,(_Float16)a.w,
                             (_Float16)b.x,(_Float16)b.y,(_Float16)b.z,(_Float16)b.w };
    }

    ushort* sw_base = &S[wave][0];
    #pragma unroll
    for (int nf=0; nf<16; ++nf){
        f32x4v acc = (f32x4v){0.f,0.f,0.f,0.f};
        #pragma unroll
        for (int ks=0; ks<4; ++ks){
            const ushort* bp = Wt + (size_t)(nf*16 + l15)*128 + ks*32 + l4*8;
            f16x8 bf = *(const f16x8*)(const void*)bp;
            // mfma(B,A): lane holds D[cols = nf*16 + l4*4 + 0..3][row = l15]
            acc = __builtin_amdgcn_mfma_f32_16x16x32_f16(bf, afrag[ks], acc, 0,0,0);
        }
        int c0 = nf*16 + l4*4;
        const float* bp2 = (c0 < 128) ? (bl + c0) : (br + (c0-128));
        float4 bv = *(const float4*)bp2;
        h2 p0 = { (_Float16)(acc[0] + bv.x), (_Float16)(acc[1] + bv.y) };
        h2 p1 = { (_Float16)(acc[2] + bv.z), (_Float16)(acc[3] + bv.w) };
        int sw = c0 ^ ((l15 & 7) << 2);           // 4-ushort-granule swizzle
        *(uint2*)(&sw_base[l15*256 + sw]) = make_uint2(__builtin_bit_cast(unsigned, p0),
                                                       __builtin_bit_cast(unsigned, p1));
    }
    __syncthreads();

    // coalesced store: per pass, 4 rows x 16 chunks(16B); lane = l4*16+l15 -> row=l4, chunk=l15
    #pragma unroll
    for (int pass=0; pass<4; ++pass){
        int row = pass*4 + l4;
        int gr = row0 + row;
        if (gr < Nn){
            int cu = l15*8;                       // ushort col within a 128-col half
            int m = (row & 7) << 2;
            uint2 a0 = *(const uint2*)(&sw_base[row*256 + (cu ^ m)]);
            uint2 a1 = *(const uint2*)(&sw_base[row*256 + ((cu+4) ^ m)]);
            *(uint4*)(xl + (size_t)gr*128 + cu) = make_uint4(a0.x, a0.y, a1.x, a1.y);
            uint2 b0 = *(const uint2*)(&sw_base[row*256 + ((128+cu) ^ m)]);
            uint2 b1 = *(const uint2*)(&sw_base[row*256 + ((128+cu+4) ^ m)]);
            *(uint4*)(xr + (size_t)gr*128 + cu) = make_uint4(b0.x, b0.y, b1.x, b1.y);
        }
    }
}

// ---------------- K3: CSR fill, packed src|etype (atomics directly on csr_next) ----------------
__global__ __launch_bounds__(256) void k_fill(const int* __restrict__ src, const int* __restrict__ dst,
    const unsigned char* __restrict__ etype_e,
    int* __restrict__ csr_next, int* __restrict__ csr_pack, int E)
{
    int e = blockIdx.x*256 + threadIdx.x;
    if (e >= E) return;
    int d = dst[e];
    int slot = atomicAdd(&csr_next[d], 1);
    csr_pack[slot] = src[e] | ((int)etype_e[e] << 24);
}

// ---------------- K4: fused per-node pass, packed f16, 4 edges in flight, 2 waves/block ----------------
// lane: g = lane>>4 (edge slot), l = lane&15 (channels l*8..l*8+7, head l>>1)
__global__ __launch_bounds__(128) void k_node(const int* __restrict__ deg_i, const int* __restrict__ csr_off,
    const int* __restrict__ csr_pack,
    const ushort* __restrict__ xl, const ushort* __restrict__ xr, const ushort* __restrict__ Web,
    const ushort* __restrict__ att_h, const float* __restrict__ att,
    const unsigned long long* __restrict__ cnt64,
    const float* __restrict__ bias, const float* __restrict__ lnw, const float* __restrict__ lnb,
    float* __restrict__ out, int Nn)
{
    int wv = threadIdx.x >> 6, lane = threadIdx.x & 63;
    int n = blockIdx.x*2 + wv;
    if (n >= Nn) return;
    int g = lane >> 4, l = lane & 15;

    h2 xr2[4], at2[4];
    {
        uint4 ru = *(const uint4*)(xr + (size_t)n*128 + l*8);
        uint4 au = *(const uint4*)(att_h + l*8);
        xr2[0]=uash2(ru.x); xr2[1]=uash2(ru.y); xr2[2]=uash2(ru.z); xr2[3]=uash2(ru.w);
        at2[0]=uash2(au.x); at2[1]=uash2(au.y); at2[2]=uash2(au.z); at2[3]=uash2(au.w);
    }
    const h2 z2  = {(_Float16)0.f, (_Float16)0.f};
    const h2 c02 = {(_Float16)NEG_SLOPE, (_Float16)NEG_SLOPE};

    int beg = csr_off[n];
    int cnt = deg_i[n];
    f32x2 acc2[4];
    #pragma unroll
    for (int k=0;k<4;++k) acc2[k] = (f32x2){0.f,0.f};
    float den = 0.f;

    #pragma unroll 2
    for (int i = 0; i < cnt; i += 4) {
        bool valid = (i + g) < cnt;
        int packed = csr_pack[beg + (valid ? i + g : 0)];
        int sidx = packed & 0xFFFFFF;
        int et = ((unsigned)packed) >> 24;
        uint4 xu = *(const uint4*)(xl + (size_t)sidx*128 + l*8);
        uint4 wu = *(const uint4*)(Web + (size_t)et*128 + l*8);
        h2 xs[4] = {uash2(xu.x), uash2(xu.y), uash2(xu.z), uash2(xu.w)};
        h2 ws[4] = {uash2(wu.x), uash2(wu.y), uash2(wu.z), uash2(wu.w)};
        float p = 0.f;
        f32x2 xf[4];
        #pragma unroll
        for (int k=0;k<4;++k){
            h2 v = (xs[k] + xr2[k]) + ws[k];
            h2 r = __builtin_elementwise_max(v, z2);
            h2 m = __builtin_elementwise_min(v, z2);
            r = r + c02*m;                                  // pk_fma
            p = __builtin_amdgcn_fdot2(at2[k], r, p, false);
            xf[k] = __builtin_convertvector(xs[k], f32x2);
        }
        p += __shfl_xor(p, 1);                              // head score (2 lanes/head)
        float ex = valid ? __expf(p) : 0.f;
        den += ex;
        #pragma unroll
        for (int k=0;k<4;++k) acc2[k] += ex * xf[k];
    }

    // cross-edge-group reduce: all 4 groups identical after this
    #pragma unroll
    for (int k=0;k<4;++k){
        acc2[k].x += __shfl_xor(acc2[k].x, 16); acc2[k].x += __shfl_xor(acc2[k].x, 32);
        acc2[k].y += __shfl_xor(acc2[k].y, 16); acc2[k].y += __shfl_xor(acc2[k].y, 32);
    }
    den += __shfl_xor(den, 16);
    den += __shfl_xor(den, 32);

    // self loop (f32 path, once per node); mean attr decoded from cnt64 byte counts
    {
        f32x2 xsf[4], xrf[4], av[4], emb[4];
        uint4 su = *(const uint4*)(xl + (size_t)n*128 + l*8);
        xsf[0]=__builtin_convertvector(uash2(su.x), f32x2); xsf[1]=__builtin_convertvector(uash2(su.y), f32x2);
        xsf[2]=__builtin_convertvector(uash2(su.z), f32x2); xsf[3]=__builtin_convertvector(uash2(su.w), f32x2);
        #pragma unroll
        for (int k=0;k<4;++k){ xrf[k]=__builtin_convertvector(xr2[k], f32x2); emb[k]=(f32x2){0.f,0.f}; }
        float4 a0 = *(const float4*)(att + l*8);
        float4 a1 = *(const float4*)(att + l*8 + 4);
        av[0]=(f32x2){a0.x,a0.y}; av[1]=(f32x2){a0.z,a0.w}; av[2]=(f32x2){a1.x,a1.y}; av[3]=(f32x2){a1.z,a1.w};
        unsigned long long cv = cnt64[n];
        float inv = 1.f / fmaxf((float)cnt, 1.f);
        #pragma unroll
        for (int t=0;t<8;++t){
            float w = (float)((cv >> (8*t)) & 0xff) * inv;
            uint4 wu = *(const uint4*)(Web + t*128 + l*8);
            emb[0] += w*__builtin_convertvector(uash2(wu.x), f32x2);
            emb[1] += w*__builtin_convertvector(uash2(wu.y), f32x2);
            emb[2] += w*__builtin_convertvector(uash2(wu.z), f32x2);
            emb[3] += w*__builtin_convertvector(uash2(wu.w), f32x2);
        }
        float p = 0.f;
        #pragma unroll
        for (int k=0;k<4;++k){
            f32x2 v = xsf[k] + xrf[k] + emb[k];
            p += av[k].x*lrelu(v.x) + av[k].y*lrelu(v.y);
        }
        p += __shfl_xor(p, 1);
        float ex = __expf(p);
        den += ex;
        #pragma unroll
        for (int k=0;k<4;++k) acc2[k] += ex * xsf[k];
    }

    float dinv = 1.f/den;
    f32x2 a[4];
    {
        float4 b0 = *(const float4*)(bias + l*8);
        float4 b1 = *(const float4*)(bias + l*8 + 4);
        a[0] = acc2[0]*dinv + (f32x2){b0.x,b0.y};
        a[1] = acc2[1]*dinv + (f32x2){b0.z,b0.w};
        a[2] = acc2[2]*dinv + (f32x2){b1.x,b1.y};
        a[3] = acc2[3]*dinv + (f32x2){b1.z,b1.w};
    }
    float sum = 0.f;
    #pragma unroll
    for (int k=0;k<4;++k) sum += a[k].x + a[k].y;
    #pragma unroll
    for (int off=8; off>0; off>>=1) sum += __shfl_xor(sum, off);
    float mu = sum * (1.f/128.f);
    float vs = 0.f;
    #pragma unroll
    for (int k=0;k<4;++k){ a[k] -= mu; vs += a[k].x*a[k].x + a[k].y*a[k].y; }
    #pragma unroll
    for (int off=8; off>0; off>>=1) vs += __shfl_xor(vs, off);
    float rs = rsqrtf(vs*(1.f/128.f) + 1e-5f);
    float y[8];
    {
        float4 w0 = *(const float4*)(lnw + l*8);
        float4 w1 = *(const float4*)(lnw + l*8 + 4);
        float4 c0 = *(const float4*)(lnb + l*8);
        float4 c1 = *(const float4*)(lnb + l*8 + 4);
        y[0]=a[0].x*rs*w0.x+c0.x; y[1]=a[0].y*rs*w0.y+c0.y;
        y[2]=a[1].x*rs*w0.z+c0.z; y[3]=a[1].y*rs*w0.w+c0.w;
        y[4]=a[2].x*rs*w1.x+c1.x; y[5]=a[2].y*rs*w1.y+c1.y;
        y[6]=a[3].x*rs*w1.z+c1.z; y[7]=a[3].y*rs*w1.w+c1.w;
    }
    #pragma unroll
    for (int j=0;j<8;++j) y[j] = (y[j] > 0.f) ? y[j] : (__expf(y[j]) - 1.f);
    if (lane < 16) {
        float* po = out + (size_t)n*128 + l*8;
        *(float4*)po     = make_float4(y[0],y[1],y[2],y[3]);
        *(float4*)(po+4) = make_float4(y[4],y[5],y[6],y[7]);
    }
}

extern "C" void kernel_launch(void* const* d_in, const int* in_sizes, int n_in,
                              void* d_out, int out_size, void* d_ws, size_t ws_size,
                              hipStream_t stream)
{
    const float* x   = (const float*)d_in[0];
    const int*   src = (const int*)  d_in[1];
    const int*   dst = (const int*)  d_in[2];
    const float* ea  = (const float*)d_in[3];
    const float* Wl  = (const float*)d_in[4];
    const float* bl  = (const float*)d_in[5];
    const float* Wr  = (const float*)d_in[6];
    const float* br  = (const float*)d_in[7];
    const float* We  = (const float*)d_in[8];
    const float* att = (const float*)d_in[9];
    const float* bias= (const float*)d_in[10];
    const float* lnw = (const float*)d_in[11];
    const float* lnb = (const float*)d_in[12];
    float* out = (float*)d_out;

    const int N  = in_sizes[0] / 128;
    const int E  = in_sizes[1];
    const int NP = ((N + 255)/256)*256;
    const int MB = (N + 63)/64;
    const int SB = NP/256;
    const int EB = (E + 255)/256;

    char* base = (char*)d_ws;
    size_t o = 0;
    auto alloc = [&](size_t b){ size_t r = o; o += (b + 255) & ~(size_t)255; return r; };
    ushort* Wt       = (ushort*)(base + alloc(256*128*2));
    ushort* Web      = (ushort*)(base + alloc(8*128*2));
    ushort* att_h    = (ushort*)(base + alloc(128*2));
    ushort* xl       = (ushort*)(base + alloc((size_t)MB*64*128*2));
    ushort* xr       = (ushort*)(base + alloc((size_t)MB*64*128*2));
    size_t zoff = o;
    unsigned long long* cnt64 = (unsigned long long*)(base + alloc((size_t)NP*8));
    int*    gtotal   = (int*)   (base + alloc(256));
    size_t zbytes = o - zoff;
    int*    deg_i    = (int*)   (base + alloc((size_t)NP*4));
    int*    csr_off  = (int*)   (base + alloc((size_t)NP*4));
    int*    csr_next = (int*)   (base + alloc((size_t)NP*4));
    int*    csr_pack = (int*)   (base + alloc((size_t)E*4));
    unsigned char* etype_e = (unsigned char*)(base + alloc((size_t)E));
    (void)ws_size; (void)n_in; (void)out_size;

    hipMemsetAsync(base + zoff, 0, zbytes, stream);
    k_prep <<<EB, 256, 0, stream>>>(Wl, Wr, We, att, Wt, Web, att_h, dst, ea, cnt64, etype_e, E);
    k_scan <<<SB, 256, 0, stream>>>(cnt64, deg_i, csr_off, csr_next, gtotal);
    k_gemm <<<MB, 256, 0, stream>>>(x, Wt, bl, br, xl, xr, N);
    k_fill <<<EB, 256, 0, stream>>>(src, dst, etype_e, csr_next, csr_pack, E);
    k_node <<<(N+1)/2, 128, 0, stream>>>(deg_i, csr_off, csr_pack, xl, xr, Web, att_h, att, cnt64,
                                         bias, lnw, lnb, out, N);
}

// Round 11
// 200.019 us; speedup vs baseline: 1.4147x; 1.1086x over previous
//
#include <hip/hip_runtime.h>
#include <hip/hip_bf16.h>

typedef _Float16 f16x8 __attribute__((ext_vector_type(8)));
typedef _Float16 h2    __attribute__((ext_vector_type(2)));
typedef float    f32x4v __attribute__((ext_vector_type(4)));
typedef float    f32x2 __attribute__((ext_vector_type(2)));

#define NEG_SLOPE 0.2f

__device__ __forceinline__ ushort f2h_bits(float f){ _Float16 h=(_Float16)f; return __builtin_bit_cast(ushort, h); }
__device__ __forceinline__ h2 uash2(unsigned u){ return __builtin_bit_cast(h2, u); }
__device__ __forceinline__ float lrelu(float v){ return fmaxf(v,0.f) + NEG_SLOPE*fminf(v,0.f); }

// ---------------- K0: prep — Wt (f16), Web (f16), att_h (f16), cnt64/etype (ONE atomic per edge) ----------------
__global__ __launch_bounds__(256) void k_prep(const float* __restrict__ Wl, const float* __restrict__ Wr,
    const float* __restrict__ We, const float* __restrict__ att,
    ushort* __restrict__ Wt, ushort* __restrict__ Web, ushort* __restrict__ att_h,
    const int* __restrict__ dst, const float* __restrict__ ea,
    unsigned long long* __restrict__ cnt64, unsigned char* __restrict__ etype_e, int E)
{
    int idx = blockIdx.x*256 + threadIdx.x;
    if (idx < 256*128) {
        int c = idx >> 7, k = idx & 127;
        float v = (c < 128) ? Wl[k*128 + c] : Wr[k*128 + (c-128)];
        Wt[idx] = f2h_bits(v);
    }
    if (idx < 8*128) Web[idx] = f2h_bits(We[idx]);
    if (idx < 128)   att_h[idx] = f2h_bits(att[idx]);
    if (idx >= E) return;
    int d = dst[idx];
    const float* a = ea + (size_t)idx*8;
    float4 u0 = *(const float4*)a;
    float4 u1 = *(const float4*)(a + 4);
    float v[8] = {u0.x,u0.y,u0.z,u0.w,u1.x,u1.y,u1.z,u1.w};
    int bt = 0;                                   // one-hot: find the nonzero component (value==1.0)
    #pragma unroll
    for (int j=0;j<8;++j) if (v[j] != 0.f) bt = j;
    etype_e[idx] = (unsigned char)bt;
    atomicAdd(&cnt64[d], 1ull << (8*bt));         // per-type count; deg = byte-sum
}

// ---------------- K1: scan — deg from cnt64, block scan + atomic base; emits deg/csr_off/csr_next ----------------
__global__ __launch_bounds__(256) void k_scan(const unsigned long long* __restrict__ cnt64,
                                              int* __restrict__ deg_i, int* __restrict__ csr_off,
                                              int* __restrict__ csr_next, int* __restrict__ gtotal)
{
    __shared__ int s[256];
    __shared__ int sbase;
    int i = blockIdx.x*256 + threadIdx.x;
    unsigned long long cv = cnt64[i];
    int v = (int)((cv * 0x0101010101010101ull) >> 56);   // byte sum = degree
    deg_i[i] = v;
    s[threadIdx.x] = v;
    __syncthreads();
    #pragma unroll
    for (int off=1; off<256; off<<=1){
        int t = (threadIdx.x >= off) ? s[threadIdx.x-off] : 0;
        __syncthreads();
        s[threadIdx.x] += t;
        __syncthreads();
    }
    if (threadIdx.x == 255) sbase = atomicAdd(gtotal, s[255]);
    __syncthreads();
    int o = s[threadIdx.x] - v + sbase;           // exclusive global offset (segment order arbitrary)
    csr_off[i]  = o;
    csr_next[i] = o;
}

// ---------------- K2: MFMA GEMM (wave-independent 16-row strips) + fused self-loop score ----------------
__global__ __launch_bounds__(256) void k_gemm(const float* __restrict__ x, const ushort* __restrict__ Wt,
    const float* __restrict__ bl, const float* __restrict__ br,
    const ushort* __restrict__ Web, const ushort* __restrict__ att_h,
    const unsigned long long* __restrict__ cnt64,
    ushort* __restrict__ xl, ushort* __restrict__ xr, float* __restrict__ expd_self, int Nn)
{
    __shared__ ushort S[4][16*256];               // 8KB per wave
    int tid = threadIdx.x;
    int wave = tid >> 6, lane = tid & 63;
    int l15 = lane & 15, l4 = lane >> 4;
    int row0 = blockIdx.x*64 + wave*16;

    // A fragments: lane holds x[row0+l15][k = ks*32 + l4*8 .. +7] as f16
    f16x8 afrag[4];
    int grow = row0 + l15;
    bool rok = grow < Nn;
    const float* xp = x + (size_t)grow*128 + l4*8;
    #pragma unroll
    for (int ks=0; ks<4; ++ks){
        float4 a = make_float4(0,0,0,0), b = make_float4(0,0,0,0);
        if (rok) { a = *(const float4*)(xp + ks*32); b = *(const float4*)(xp + ks*32 + 4); }
        afrag[ks] = (f16x8){ (_Float16)a.x,(_Float16)a.y,(_Float16)a.z,(_Float16)a.w,
                             (_Float16)b.x,(_Float16)b.y,(_Float16)b.z,(_Float16)b.w };
    }

    ushort* sw_base = &S[wave][0];
    #pragma unroll
    for (int nf=0; nf<16; ++nf){
        f32x4v acc = (f32x4v){0.f,0.f,0.f,0.f};
        #pragma unroll
        for (int ks=0; ks<4; ++ks){
            const ushort* bp = Wt + (size_t)(nf*16 + l15)*128 + ks*32 + l4*8;
            f16x8 bf = *(const f16x8*)(const void*)bp;
            // mfma(B,A): lane holds D[cols = nf*16 + l4*4 + 0..3][row = l15]
            acc = __builtin_amdgcn_mfma_f32_16x16x32_f16(bf, afrag[ks], acc, 0,0,0);
        }
        int c0 = nf*16 + l4*4;
        const float* bp2 = (c0 < 128) ? (bl + c0) : (br + (c0-128));
        float4 bv = *(const float4*)bp2;
        h2 p0 = { (_Float16)(acc[0] + bv.x), (_Float16)(acc[1] + bv.y) };
        h2 p1 = { (_Float16)(acc[2] + bv.z), (_Float16)(acc[3] + bv.w) };
        int sw = c0 ^ ((l15 & 7) << 2);           // 4-ushort-granule swizzle
        *(uint2*)(&sw_base[l15*256 + sw]) = make_uint2(__builtin_bit_cast(unsigned, p0),
                                                       __builtin_bit_cast(unsigned, p1));
    }
    __syncthreads();

    // coalesced store: per pass, 4 rows x 16 chunks(16B); lane = l4*16+l15 -> row=l4, chunk=l15
    #pragma unroll
    for (int pass=0; pass<4; ++pass){
        int row = pass*4 + l4;
        int gr = row0 + row;
        if (gr < Nn){
            int cu = l15*8;                       // ushort col within a 128-col half
            int m = (row & 7) << 2;
            uint2 a0 = *(const uint2*)(&sw_base[row*256 + (cu ^ m)]);
            uint2 a1 = *(const uint2*)(&sw_base[row*256 + ((cu+4) ^ m)]);
            *(uint4*)(xl + (size_t)gr*128 + cu) = make_uint4(a0.x, a0.y, a1.x, a1.y);
            uint2 b0 = *(const uint2*)(&sw_base[row*256 + ((128+cu) ^ m)]);
            uint2 b1 = *(const uint2*)(&sw_base[row*256 + ((128+cu+4) ^ m)]);
            *(uint4*)(xr + (size_t)gr*128 + cu) = make_uint4(b0.x, b0.y, b1.x, b1.y);
        }
    }

    // Fused self-loop score: lane (q=l4, row=l15) covers channels q*32..q*32+31 = heads 2q, 2q+1.
    if (rok) {
        unsigned long long cv = cnt64[grow];
        int deg = (int)((cv * 0x0101010101010101ull) >> 56);
        float inv = 1.f / fmaxf((float)deg, 1.f);
        h2 wt[8];
        #pragma unroll
        for (int t=0;t<8;++t){
            float w = (float)((cv >> (8*t)) & 0xff) * inv;
            wt[t] = (h2){ (_Float16)w, (_Float16)w };
        }
        h2 emb[16];
        #pragma unroll
        for (int j=0;j<16;++j) emb[j] = (h2){(_Float16)0.f,(_Float16)0.f};
        #pragma unroll
        for (int t=0;t<8;++t){
            const ushort* wp = Web + t*128 + l4*32;
            uint4 u0 = *(const uint4*)wp;
            uint4 u1 = *(const uint4*)(wp + 8);
            uint4 u2 = *(const uint4*)(wp + 16);
            uint4 u3 = *(const uint4*)(wp + 24);
            emb[0]+=wt[t]*uash2(u0.x); emb[1]+=wt[t]*uash2(u0.y); emb[2]+=wt[t]*uash2(u0.z); emb[3]+=wt[t]*uash2(u0.w);
            emb[4]+=wt[t]*uash2(u1.x); emb[5]+=wt[t]*uash2(u1.y); emb[6]+=wt[t]*uash2(u1.z); emb[7]+=wt[t]*uash2(u1.w);
            emb[8]+=wt[t]*uash2(u2.x); emb[9]+=wt[t]*uash2(u2.y); emb[10]+=wt[t]*uash2(u2.z); emb[11]+=wt[t]*uash2(u2.w);
            emb[12]+=wt[t]*uash2(u3.x); emb[13]+=wt[t]*uash2(u3.y); emb[14]+=wt[t]*uash2(u3.z); emb[15]+=wt[t]*uash2(u3.w);
        }
        h2 at2v[16];
        {
            const ushort* ap = att_h + l4*32;
            uint4 a0 = *(const uint4*)ap;
            uint4 a1 = *(const uint4*)(ap + 8);
            uint4 a2 = *(const uint4*)(ap + 16);
            uint4 a3 = *(const uint4*)(ap + 24);
            at2v[0]=uash2(a0.x); at2v[1]=uash2(a0.y); at2v[2]=uash2(a0.z); at2v[3]=uash2(a0.w);
            at2v[4]=uash2(a1.x); at2v[5]=uash2(a1.y); at2v[6]=uash2(a1.z); at2v[7]=uash2(a1.w);
            at2v[8]=uash2(a2.x); at2v[9]=uash2(a2.y); at2v[10]=uash2(a2.z); at2v[11]=uash2(a2.w);
            at2v[12]=uash2(a3.x); at2v[13]=uash2(a3.y); at2v[14]=uash2(a3.z); at2v[15]=uash2(a3.w);
        }
        const h2 z2  = {(_Float16)0.f, (_Float16)0.f};
        const h2 c02 = {(_Float16)NEG_SLOPE, (_Float16)NEG_SLOPE};
        float p0 = 0.f, p1 = 0.f;
        int m = (l15 & 7) << 2;
        #pragma unroll
        for (int j=0;j<8;++j){
            int c0 = l4*32 + j*4;
            uint2 xlu = *(const uint2*)(&sw_base[l15*256 + (c0 ^ m)]);
            uint2 xru = *(const uint2*)(&sw_base[l15*256 + ((128+c0) ^ m)]);
            #pragma unroll
            for (int s2=0;s2<2;++s2){
                h2 v = (uash2(s2 ? xlu.y : xlu.x) + uash2(s2 ? xru.y : xru.x)) + emb[j*2+s2];
                h2 r = __builtin_elementwise_max(v, z2);
                h2 mm = __builtin_elementwise_min(v, z2);
                r = r + c02*mm;
                if (j < 4) p0 = __builtin_amdgcn_fdot2(at2v[j*2+s2], r, p0, false);
                else       p1 = __builtin_amdgcn_fdot2(at2v[j*2+s2], r, p1, false);
            }
        }
        *(float2*)(expd_self + (size_t)grow*8 + l4*2) = make_float2(__expf(p0), __expf(p1));
    }
}

// ---------------- K3: CSR fill, packed src|etype (atomics directly on csr_next) ----------------
__global__ __launch_bounds__(256) void k_fill(const int* __restrict__ src, const int* __restrict__ dst,
    const unsigned char* __restrict__ etype_e,
    int* __restrict__ csr_next, int* __restrict__ csr_pack, int E)
{
    int e = blockIdx.x*256 + threadIdx.x;
    if (e >= E) return;
    int d = dst[e];
    int slot = atomicAdd(&csr_next[d], 1);
    csr_pack[slot] = src[e] | ((int)etype_e[e] << 24);
}

// ---------------- K4: fused per-node pass, packed f16, 4 edges in flight, 2 waves/block ----------------
// lane: g = lane>>4 (edge slot), l = lane&15 (channels l*8..l*8+7, head l>>1)
__global__ __launch_bounds__(128) void k_node(const int* __restrict__ deg_i, const int* __restrict__ csr_off,
    const int* __restrict__ csr_pack,
    const ushort* __restrict__ xl, const ushort* __restrict__ xr, const ushort* __restrict__ Web,
    const ushort* __restrict__ att_h, const float* __restrict__ expd_self,
    const float* __restrict__ bias, const float* __restrict__ lnw, const float* __restrict__ lnb,
    float* __restrict__ out, int Nn)
{
    int wv = threadIdx.x >> 6, lane = threadIdx.x & 63;
    int n = blockIdx.x*2 + wv;
    if (n >= Nn) return;
    int g = lane >> 4, l = lane & 15;

    h2 xr2[4], at2[4];
    {
        uint4 ru = *(const uint4*)(xr + (size_t)n*128 + l*8);
        uint4 au = *(const uint4*)(att_h + l*8);
        xr2[0]=uash2(ru.x); xr2[1]=uash2(ru.y); xr2[2]=uash2(ru.z); xr2[3]=uash2(ru.w);
        at2[0]=uash2(au.x); at2[1]=uash2(au.y); at2[2]=uash2(au.z); at2[3]=uash2(au.w);
    }
    const h2 z2  = {(_Float16)0.f, (_Float16)0.f};
    const h2 c02 = {(_Float16)NEG_SLOPE, (_Float16)NEG_SLOPE};

    int beg = csr_off[n];
    int cnt = deg_i[n];
    f32x2 acc2[4];
    #pragma unroll
    for (int k=0;k<4;++k) acc2[k] = (f32x2){0.f,0.f};
    float den = 0.f;

    #pragma unroll 2
    for (int i = 0; i < cnt; i += 4) {
        bool valid = (i + g) < cnt;
        int packed = csr_pack[beg + (valid ? i + g : 0)];
        int sidx = packed & 0xFFFFFF;
        int et = ((unsigned)packed) >> 24;
        uint4 xu = *(const uint4*)(xl + (size_t)sidx*128 + l*8);
        uint4 wu = *(const uint4*)(Web + (size_t)et*128 + l*8);
        h2 xs[4] = {uash2(xu.x), uash2(xu.y), uash2(xu.z), uash2(xu.w)};
        h2 ws[4] = {uash2(wu.x), uash2(wu.y), uash2(wu.z), uash2(wu.w)};
        float p = 0.f;
        f32x2 xf[4];
        #pragma unroll
        for (int k=0;k<4;++k){
            h2 v = (xs[k] + xr2[k]) + ws[k];
            h2 r = __builtin_elementwise_max(v, z2);
            h2 m = __builtin_elementwise_min(v, z2);
            r = r + c02*m;                                  // pk_fma
            p = __builtin_amdgcn_fdot2(at2[k], r, p, false);
            xf[k] = __builtin_convertvector(xs[k], f32x2);
        }
        p += __shfl_xor(p, 1);                              // head score (2 lanes/head)
        float ex = valid ? __expf(p) : 0.f;
        den += ex;
        #pragma unroll
        for (int k=0;k<4;++k) acc2[k] += ex * xf[k];
    }

    // cross-edge-group reduce: all 4 groups identical after this
    #pragma unroll
    for (int k=0;k<4;++k){
        acc2[k].x += __shfl_xor(acc2[k].x, 16); acc2[k].x += __shfl_xor(acc2[k].x, 32);
        acc2[k].y += __shfl_xor(acc2[k].y, 16); acc2[k].y += __shfl_xor(acc2[k].y, 32);
    }
    den += __shfl_xor(den, 16);
    den += __shfl_xor(den, 32);

    // self loop: expd_self precomputed in k_gemm
    {
        float ex = expd_self[(size_t)n*8 + (l >> 1)];
        uint4 su = *(const uint4*)(xl + (size_t)n*128 + l*8);
        den += ex;
        acc2[0] += ex*__builtin_convertvector(uash2(su.x), f32x2);
        acc2[1] += ex*__builtin_convertvector(uash2(su.y), f32x2);
        acc2[2] += ex*__builtin_convertvector(uash2(su.z), f32x2);
        acc2[3] += ex*__builtin_convertvector(uash2(su.w), f32x2);
    }

    float dinv = 1.f/den;
    f32x2 a[4];
    {
        float4 b0 = *(const float4*)(bias + l*8);
        float4 b1 = *(const float4*)(bias + l*8 + 4);
        a[0] = acc2[0]*dinv + (f32x2){b0.x,b0.y};
        a[1] = acc2[1]*dinv + (f32x2){b0.z,b0.w};
        a[2] = acc2[2]*dinv + (f32x2){b1.x,b1.y};
        a[3] = acc2[3]*dinv + (f32x2){b1.z,b1.w};
    }
    float sum = 0.f;
    #pragma unroll
    for (int k=0;k<4;++k) sum += a[k].x + a[k].y;
    #pragma unroll
    for (int off=8; off>0; off>>=1) sum += __shfl_xor(sum, off);
    float mu = sum * (1.f/128.f);
    float vs = 0.f;
    #pragma unroll
    for (int k=0;k<4;++k){ a[k] -= mu; vs += a[k].x*a[k].x + a[k].y*a[k].y; }
    #pragma unroll
    for (int off=8; off>0; off>>=1) vs += __shfl_xor(vs, off);
    float rs = rsqrtf(vs*(1.f/128.f) + 1e-5f);
    float y[8];
    {
        float4 w0 = *(const float4*)(lnw + l*8);
        float4 w1 = *(const float4*)(lnw + l*8 + 4);
        float4 c0 = *(const float4*)(lnb + l*8);
        float4 c1 = *(const float4*)(lnb + l*8 + 4);
        y[0]=a[0].x*rs*w0.x+c0.x; y[1]=a[0].y*rs*w0.y+c0.y;
        y[2]=a[1].x*rs*w0.z+c0.z; y[3]=a[1].y*rs*w0.w+c0.w;
        y[4]=a[2].x*rs*w1.x+c1.x; y[5]=a[2].y*rs*w1.y+c1.y;
        y[6]=a[3].x*rs*w1.z+c1.z; y[7]=a[3].y*rs*w1.w+c1.w;
    }
    #pragma unroll
    for (int j=0;j<8;++j) y[j] = (y[j] > 0.f) ? y[j] : (__expf(y[j]) - 1.f);
    if (lane < 16) {
        float* po = out + (size_t)n*128 + l*8;
        *(float4*)po     = make_float4(y[0],y[1],y[2],y[3]);
        *(float4*)(po+4) = make_float4(y[4],y[5],y[6],y[7]);
    }
}

extern "C" void kernel_launch(void* const* d_in, const int* in_sizes, int n_in,
                              void* d_out, int out_size, void* d_ws, size_t ws_size,
                              hipStream_t stream)
{
    const float* x   = (const float*)d_in[0];
    const int*   src = (const int*)  d_in[1];
    const int*   dst = (const int*)  d_in[2];
    const float* ea  = (const float*)d_in[3];
    const float* Wl  = (const float*)d_in[4];
    const float* bl  = (const float*)d_in[5];
    const float* Wr  = (const float*)d_in[6];
    const float* br  = (const float*)d_in[7];
    const float* We  = (const float*)d_in[8];
    const float* att = (const float*)d_in[9];
    const float* bias= (const float*)d_in[10];
    const float* lnw = (const float*)d_in[11];
    const float* lnb = (const float*)d_in[12];
    float* out = (float*)d_out;

    const int N  = in_sizes[0] / 128;
    const int E  = in_sizes[1];
    const int NP = ((N + 255)/256)*256;
    const int MB = (N + 63)/64;
    const int SB = NP/256;
    const int EB = (E + 255)/256;

    char* base = (char*)d_ws;
    size_t o = 0;
    auto alloc = [&](size_t b){ size_t r = o; o += (b + 255) & ~(size_t)255; return r; };
    ushort* Wt       = (ushort*)(base + alloc(256*128*2));
    ushort* Web      = (ushort*)(base + alloc(8*128*2));
    ushort* att_h    = (ushort*)(base + alloc(128*2));
    ushort* xl       = (ushort*)(base + alloc((size_t)MB*64*128*2));
    ushort* xr       = (ushort*)(base + alloc((size_t)MB*64*128*2));
    float*  expd_self= (float*) (base + alloc((size_t)NP*8*4));
    size_t zoff = o;
    unsigned long long* cnt64 = (unsigned long long*)(base + alloc((size_t)NP*8));
    int*    gtotal   = (int*)   (base + alloc(256));
    size_t zbytes = o - zoff;
    int*    deg_i    = (int*)   (base + alloc((size_t)NP*4));
    int*    csr_off  = (int*)   (base + alloc((size_t)NP*4));
    int*    csr_next = (int*)   (base + alloc((size_t)NP*4));
    int*    csr_pack = (int*)   (base + alloc((size_t)E*4));
    unsigned char* etype_e = (unsigned char*)(base + alloc((size_t)E));
    (void)ws_size; (void)n_in; (void)out_size;

    hipMemsetAsync(base + zoff, 0, zbytes, stream);
    k_prep <<<EB, 256, 0, stream>>>(Wl, Wr, We, att, Wt, Web, att_h, dst, ea, cnt64, etype_e, E);
    k_scan <<<SB, 256, 0, stream>>>(cnt64, deg_i, csr_off, csr_next, gtotal);
    k_gemm <<<MB, 256, 0, stream>>>(x, Wt, bl, br, Web, att_h, cnt64, xl, xr, expd_self, N);
    k_fill <<<EB, 256, 0, stream>>>(src, dst, etype_e, csr_next, csr_pack, E);
    k_node <<<(N+1)/2, 128, 0, stream>>>(deg_i, csr_off, csr_pack, xl, xr, Web, att_h, expd_self,
                                         bias, lnw, lnb, out, N);
}